// Round 3
// baseline (205.442 us; speedup 1.0000x reference)
//
#include <hip/hip_runtime.h>

// ---------------------------------------------------------------------------
// x(2,32,16,16,16), w_init(32,32,27), w_qkv(96,32,27), w_out(32,32), b_out(32).
// out(2,64,4096). heads=4, dk_h=dv_h=8, N=4096, scale=8^-0.5 (folded into Q
// together with log2e; softmax uses exp2). Attention via bf16 MFMA 16x16x32.
// ---------------------------------------------------------------------------

typedef short short8 __attribute__((ext_vector_type(8)));
typedef float float4v __attribute__((ext_vector_type(4)));
typedef unsigned short ushort_t;
typedef unsigned int uint_t;

__device__ inline ushort_t f2bf(float x) {   // fp32 -> bf16 RNE
  uint_t u = __builtin_bit_cast(uint_t, x);
  u += 0x7FFFu + ((u >> 16) & 1u);
  return (ushort_t)(u >> 16);
}

// Transpose weights to wT[c_in(32)][tap(27)][o(128)]; o: 0..31 init conv,
// 32..63 q, 64..95 k, 96..127 v. Wave-uniform contiguous weight fetches.
__global__ __launch_bounds__(256) void kW(const float* __restrict__ w_init,
                                          const float* __restrict__ w_qkv,
                                          float* __restrict__ wT) {
  int idx = blockIdx.x * 256 + threadIdx.x;   // exactly 32*27*128 = 110592
  int o = idx & 127;
  int t = (idx >> 7) % 27;
  int i = idx / (128 * 27);
  float v;
  if (o < 32) v = w_init[(o * 32 + i) * 27 + t];
  else        v = w_qkv[((o - 32) * 32 + i) * 27 + t];
  wT[idx] = v;
}

// Direct circular 3x3x3 conv. Block = one (b, z-slice, group of 8 out-ch).
// Grid = 2*16*16 = 512 blocks, 256 threads (16x16 xy). Emits:
//   g 0..3   -> out channels 0..31 (fp32)
//   g 4..7   -> Qbf [bh][n][c8] bf16 (scaled by 8^-0.5 * log2e)
//   g 8..11  -> Kbf [bh][m][c8] bf16
//   g 12..15 -> VtT [bh][v8][m]  bf16 (channel-major for PV B-operand)
__global__ __launch_bounds__(256) void kConv(const float* __restrict__ x,
                                             const float* __restrict__ wT,
                                             float* __restrict__ out,
                                             ushort_t* __restrict__ Qbf,
                                             ushort_t* __restrict__ Kbf,
                                             ushort_t* __restrict__ VtT) {
  __shared__ float xs[8 * 3 * 256];   // 24 KB
  int tid = threadIdx.x;
  int bx = blockIdx.x;
  int z = bx & 15;
  int g = (bx >> 4) & 15;  // out-channel group (8 ch each)
  int b = bx >> 8;
  int x0 = tid & 15;
  int y0 = tid >> 4;

  float acc[8];
#pragma unroll
  for (int o = 0; o < 8; ++o) acc[o] = 0.f;

  for (int ic = 0; ic < 4; ++ic) {
    __syncthreads();
#pragma unroll
    for (int j = 0; j < 6; ++j) {
      int ti = j * 256 + tid;      // float4 slot in [0, 1536)
      int p = ti >> 6;             // plane [0,24)
      int quad = ti & 63;
      int i3 = p / 3;
      int zz = p - i3 * 3;
      int zr = (z + zz + 15) & 15;
      const float4 v = *(const float4*)(x + (((size_t)(b * 32 + ic * 8 + i3) * 16 + zr) * 256) + quad * 4);
      *(float4*)(xs + p * 256 + quad * 4) = v;
    }
    __syncthreads();

    for (int i = 0; i < 8; ++i) {
      const float* wbase = wT + (size_t)((ic * 8 + i) * 27) * 128 + g * 8;
#pragma unroll
      for (int kz = 0; kz < 3; ++kz) {
        const float* xp = xs + (i * 3 + kz) * 256;
#pragma unroll
        for (int ky = 0; ky < 3; ++ky) {
          int yr = (y0 + ky + 15) & 15;
#pragma unroll
          for (int kx = 0; kx < 3; ++kx) {
            int xr = (x0 + kx + 15) & 15;
            float xv = xp[yr * 16 + xr];
            const float* wrow = wbase + (kz * 9 + ky * 3 + kx) * 128;  // uniform
#pragma unroll
            for (int o = 0; o < 8; ++o) acc[o] = fmaf(xv, wrow[o], acc[o]);
          }
        }
      }
    }
  }

  int s = z * 256 + tid;   // flat spatial
  if (g < 4) {
    int o0 = g * 8;
#pragma unroll
    for (int o = 0; o < 8; ++o) out[(size_t)(b * 64 + o0 + o) * 4096 + s] = acc[o];
  } else if (g < 8) {
    const float QS = 0.35355339059327373f * 1.4426950408889634f;
    int h = g - 4;
    ushort_t tmp[8];
#pragma unroll
    for (int o = 0; o < 8; ++o) tmp[o] = f2bf(acc[o] * QS);
    *(short8*)(Qbf + ((size_t)(b * 4 + h) * 4096 + s) * 8) = *(short8*)tmp;
  } else if (g < 12) {
    int h = g - 8;
    ushort_t tmp[8];
#pragma unroll
    for (int o = 0; o < 8; ++o) tmp[o] = f2bf(acc[o]);
    *(short8*)(Kbf + ((size_t)(b * 4 + h) * 4096 + s) * 8) = *(short8*)tmp;
  } else {
    int h = g - 12;
#pragma unroll
    for (int o = 0; o < 8; ++o)
      VtT[((size_t)(b * 4 + h) * 8 + o) * 4096 + s] = f2bf(acc[o]);
  }
}

// MFMA attention. One wave per 16-row n-tile; block = 4 waves; grid = 512.
// Per 32-key chunk: 2 QK mfmas (K=32 padded from dk_h=8) -> exp2 -> bf16 P to
// per-wave LDS tile -> A-fragment read -> 1 PV mfma (K=32). The PV B-operand
// carries V channels 0..7, a ones-column at v=8 (row-sum l for free), zeros
// above. No softmax max-subtraction: |logit*log2e| <~ 12, safe in fp32.
__global__ __launch_bounds__(256) void kAttn(const ushort_t* __restrict__ Qbf,
                                             const ushort_t* __restrict__ Kbf,
                                             const ushort_t* __restrict__ VtT,
                                             float* __restrict__ attn) {
  __shared__ ushort_t Plds[4 * 2 * 16 * 40];  // 4 waves x 2 tiles x 16 rows x 40 (80B stride)
  int tid = threadIdx.x;
  int w = tid >> 6, lane = tid & 63;
  int bh = blockIdx.x >> 6;                  // [0,8)
  int n0 = (blockIdx.x & 63) * 64 + w * 16;  // this wave's 16 query rows
  int quad = lane >> 4, nl = lane & 15;
  int v = nl;

  short8 aq = {};
  if (quad == 0) aq = *(const short8*)(Qbf + ((size_t)bh * 4096 + n0 + nl) * 8);

  short8 ones8;
#pragma unroll
  for (int i = 0; i < 8; ++i) ones8[i] = (short)0x3F80;  // bf16 1.0

  const ushort_t* Krows = Kbf + (size_t)bh * 4096 * 8;
  const ushort_t* Vrow = VtT + ((size_t)bh * 8 + v) * 4096 + quad * 8;
  ushort_t* Pw = Plds + w * 2 * 640;

  float4v acc = {};
#pragma unroll 2
  for (int mi = 0; mi < 128; ++mi) {
    int m0 = mi * 32;
    short8 bk0 = {}, bk1 = {};
    if (quad == 0) {
      bk0 = *(const short8*)(Krows + (size_t)(m0 + nl) * 8);
      bk1 = *(const short8*)(Krows + (size_t)(m0 + 16 + nl) * 8);
    }
    float4v s0 = __builtin_amdgcn_mfma_f32_16x16x32_bf16(aq, bk0, (float4v){0.f, 0.f, 0.f, 0.f}, 0, 0, 0);
    float4v s1 = __builtin_amdgcn_mfma_f32_16x16x32_bf16(aq, bk1, (float4v){0.f, 0.f, 0.f, 0.f}, 0, 0, 0);
    ushort_t* Pt = Pw + (mi & 1) * 640;
    // C-layout: col = nl, row = quad*4+r. Write P tile [n16][m32] bf16.
#pragma unroll
    for (int r = 0; r < 4; ++r) {
      int row = quad * 4 + r;
      Pt[row * 40 + nl]      = f2bf(__builtin_amdgcn_exp2f(s0[r]));
      Pt[row * 40 + 16 + nl] = f2bf(__builtin_amdgcn_exp2f(s1[r]));
    }
    // A-layout read: A[n=nl][k=quad*8+j] (within-wave LDS round-trip; DS ops
    // are in-order per wave, backend inserts lgkmcnt).
    short8 a2 = *(const short8*)(Pt + nl * 40 + quad * 8);
    short8 b2;
    if (v < 8)       b2 = *(const short8*)(Vrow + m0);
    else if (v == 8) b2 = ones8;
    else             b2 = (short8){};
    acc = __builtin_amdgcn_mfma_f32_16x16x32_bf16(a2, b2, acc, 0, 0, 0);
  }

  // acc: O[n][v] at col=v=nl, row=quad*4+r; col 8 holds the row-sum l.
  int b = bh >> 2, h = bh & 3;
#pragma unroll
  for (int r = 0; r < 4; ++r) {
    float l = __shfl(acc[r], (lane & 48) | 8, 64);
    float val = acc[r] / l;
    if (v < 8) {
      int ng = n0 + quad * 4 + r;
      // faithful reshape: attn[b][h*8 + (ng>>9)][(ng&511)*8 + v]
      attn[((size_t)(b * 32 + h * 8 + (ng >> 9)) << 12) + ((ng & 511) * 8 + v)] = val;
    }
  }
}

// 1x1x1 conv + bias -> out channels 32..63. 2 out-ch per thread, 512 blocks.
__global__ __launch_bounds__(256) void kOut(const float* __restrict__ attn,
                                            const float* __restrict__ w_out,
                                            const float* __restrict__ b_out,
                                            float* __restrict__ out) {
  int idx = blockIdx.x * 256 + threadIdx.x;  // [0, 131072)
  int s = idx & 4095;
  int b = (idx >> 12) & 1;
  int cp = idx >> 13;                        // [0,16) co-pair, block-uniform
  float a[32];
#pragma unroll
  for (int ci = 0; ci < 32; ++ci) a[ci] = attn[(size_t)(b * 32 + ci) * 4096 + s];
#pragma unroll
  for (int oo = 0; oo < 2; ++oo) {
    int co = cp * 2 + oo;
    float r = b_out[co];
#pragma unroll
    for (int ci = 0; ci < 32; ++ci) r = fmaf(w_out[co * 32 + ci], a[ci], r);
    out[(size_t)(b * 64 + 32 + co) * 4096 + s] = r;
  }
}

extern "C" void kernel_launch(void* const* d_in, const int* in_sizes, int n_in,
                              void* d_out, int out_size, void* d_ws, size_t ws_size,
                              hipStream_t stream) {
  const float* x      = (const float*)d_in[0];
  const float* w_init = (const float*)d_in[1];
  const float* w_qkv  = (const float*)d_in[2];
  const float* w_out  = (const float*)d_in[3];
  const float* b_out  = (const float*)d_in[4];
  float* out = (float*)d_out;

  // ws layout: wT 110592 f | Qbf 262144 u16 | Kbf 262144 u16 | VtT 262144 u16 |
  //            attn 262144 f   (total ~3.1 MB)
  float* wT = (float*)d_ws;
  ushort_t* Qbf = (ushort_t*)(wT + 110592);
  ushort_t* Kbf = Qbf + 262144;
  ushort_t* VtT = Kbf + 262144;
  float* attn = (float*)(VtT + 262144);

  kW    <<<432, 256, 0, stream>>>(w_init, w_qkv, wT);
  kConv <<<512, 256, 0, stream>>>(x, wT, out, Qbf, Kbf, VtT);
  kAttn <<<512, 256, 0, stream>>>(Qbf, Kbf, VtT, attn);
  kOut  <<<512, 256, 0, stream>>>(attn, w_out, b_out, out);
}

// Round 5
// 155.273 us; speedup vs baseline: 1.3231x; 1.3231x over previous
//
#include <hip/hip_runtime.h>

// ---------------------------------------------------------------------------
// x(2,32,16,16,16), w_init(32,32,27), w_qkv(96,32,27), w_out(32,32), b_out(32).
// out(2,64,4096). heads=4, dk_h=dv_h=8, N=4096, scale=8^-0.5 (folded into Q
// together with log2e; softmax uses exp2). Attention via bf16 MFMA 16x16x32,
// key-split 4x for occupancy, software-pipelined P LDS round-trip.
// ---------------------------------------------------------------------------

typedef short short8 __attribute__((ext_vector_type(8)));
typedef short short4v __attribute__((ext_vector_type(4)));
typedef float float4v __attribute__((ext_vector_type(4)));
typedef unsigned short ushort_t;
typedef unsigned int uint_t;

__device__ inline ushort_t f2bf(float x) {   // fp32 -> bf16 RNE
  uint_t u = __builtin_bit_cast(uint_t, x);
  u += 0x7FFFu + ((u >> 16) & 1u);
  return (ushort_t)(u >> 16);
}

__device__ inline uint_t pk2bf(float lo, float hi) {  // packed bf16x2 dword
  return (uint_t)f2bf(lo) | ((uint_t)f2bf(hi) << 16);
}

// Transpose weights to wT[c_in(32)][tap(27)][o(128)]; o: 0..31 init conv,
// 32..63 q, 64..95 k, 96..127 v. Wave-uniform contiguous weight fetches.
__global__ __launch_bounds__(256) void kW(const float* __restrict__ w_init,
                                          const float* __restrict__ w_qkv,
                                          float* __restrict__ wT) {
  int idx = blockIdx.x * 256 + threadIdx.x;   // exactly 32*27*128 = 110592
  int o = idx & 127;
  int t = (idx >> 7) % 27;
  int i = idx / (128 * 27);
  float v;
  if (o < 32) v = w_init[(o * 32 + i) * 27 + t];
  else        v = w_qkv[((o - 32) * 32 + i) * 27 + t];
  wT[idx] = v;
}

// Direct circular 3x3x3 conv. Block = one (b, z-slice, group of 4 out-ch).
// Grid = 2*16*32 = 1024 blocks (4 blocks/CU, 16 waves/CU), 256 threads.
// Emits: g 0..7 -> out ch 0..31 (fp32); g 8..15 -> Qbf [bh][n][c8] bf16
// (scaled); g 16..23 -> Kbf [bh][m][c8] bf16; g 24..31 -> VtTp [bh][v8][m']
// bf16 with m' = within-32-chunk interleave perm (matches kAttn's P k-order).
__global__ __launch_bounds__(256) void kConv(const float* __restrict__ x,
                                             const float* __restrict__ wT,
                                             float* __restrict__ out,
                                             ushort_t* __restrict__ Qbf,
                                             ushort_t* __restrict__ Kbf,
                                             ushort_t* __restrict__ VtTp) {
  __shared__ float xs[8 * 3 * 256];   // 24 KB
  int tid = threadIdx.x;
  int bx = blockIdx.x;
  int z = bx & 15;
  int g = (bx >> 4) & 31;  // out-channel group (4 ch each)
  int b = bx >> 9;
  int x0 = tid & 15;
  int y0 = tid >> 4;

  float acc[4];
#pragma unroll
  for (int o = 0; o < 4; ++o) acc[o] = 0.f;

  for (int ic = 0; ic < 4; ++ic) {
    __syncthreads();
#pragma unroll
    for (int j = 0; j < 6; ++j) {
      int ti = j * 256 + tid;      // float4 slot in [0, 1536)
      int p = ti >> 6;             // plane [0,24)
      int quad = ti & 63;
      int i3 = p / 3;
      int zz = p - i3 * 3;
      int zr = (z + zz + 15) & 15;
      const float4 v = *(const float4*)(x + (((size_t)(b * 32 + ic * 8 + i3) * 16 + zr) * 256) + quad * 4);
      *(float4*)(xs + p * 256 + quad * 4) = v;
    }
    __syncthreads();

    for (int i = 0; i < 8; ++i) {
      const float* wbase = wT + (size_t)((ic * 8 + i) * 27) * 128 + g * 4;
#pragma unroll
      for (int kz = 0; kz < 3; ++kz) {
        const float* xp = xs + (i * 3 + kz) * 256;
#pragma unroll
        for (int ky = 0; ky < 3; ++ky) {
          int yr = (y0 + ky + 15) & 15;
#pragma unroll
          for (int kx = 0; kx < 3; ++kx) {
            int xr = (x0 + kx + 15) & 15;
            float xv = xp[yr * 16 + xr];
            const float* wrow = wbase + (kz * 9 + ky * 3 + kx) * 128;  // uniform
#pragma unroll
            for (int o = 0; o < 4; ++o) acc[o] = fmaf(xv, wrow[o], acc[o]);
          }
        }
      }
    }
  }

  int s = z * 256 + tid;   // flat spatial
  if (g < 8) {
    int o0 = g * 4;
#pragma unroll
    for (int o = 0; o < 4; ++o) out[(size_t)(b * 64 + o0 + o) * 4096 + s] = acc[o];
  } else if (g < 16) {
    const float QS = 0.35355339059327373f * 1.4426950408889634f;
    int q = g * 4 - 32;
    int h = q >> 3, c0 = q & 7;
    ushort_t tmp[4];
#pragma unroll
    for (int o = 0; o < 4; ++o) tmp[o] = f2bf(acc[o] * QS);
    *(short4v*)(Qbf + ((size_t)(b * 4 + h) * 4096 + s) * 8 + c0) = *(short4v*)tmp;
  } else if (g < 24) {
    int k = g * 4 - 64;
    int h = k >> 3, c0 = k & 7;
    ushort_t tmp[4];
#pragma unroll
    for (int o = 0; o < 4; ++o) tmp[o] = f2bf(acc[o]);
    *(short4v*)(Kbf + ((size_t)(b * 4 + h) * 4096 + s) * 8 + c0) = *(short4v*)tmp;
  } else {
    int vv = g * 4 - 96;
    int h = vv >> 3, c0 = vv & 7;
    int ml = s & 31;
    int mperm = (ml < 16) ? 2 * ml : 2 * (ml - 16) + 1;   // k'-interleave
    size_t base = (size_t)(s & ~31) + mperm;
#pragma unroll
    for (int o = 0; o < 4; ++o)
      VtTp[((size_t)(b * 4 + h) * 8 + c0 + o) * 4096 + base] = f2bf(acc[o]);
  }
}

// MFMA attention, key-split 4x. One wave = 16 query rows x 1024 keys.
// Grid = 2048 blocks x 4 waves = 8192 waves (8 blocks/CU, full occupancy).
// Pipeline: chunk i's QK->exp->packed P write goes to LDS buffer (i&1) while
// the PV mfma consumes buffer ((i-1)&1) -> the ds_read never waits on the
// current chunk. P is stored k-interleaved (cols 2m/2m+1 from tiles 0/1) so
// each lane writes ONE packed dword; V was pre-permuted identically.
// PV B-operand: V ch 0..7, ones at v=8 (row-sum l for free), zeros above.
__global__ __launch_bounds__(256) void kAttn(const ushort_t* __restrict__ Qbf,
                                             const ushort_t* __restrict__ Kbf,
                                             const ushort_t* __restrict__ VtTp,
                                             float* __restrict__ pacc,
                                             float* __restrict__ pl) {
  __shared__ ushort_t Plds[4 * 2 * 16 * 40];  // 4 waves x 2 bufs x 16 rows x 40
  int tid = threadIdx.x;
  int w = tid >> 6, lane = tid & 63;
  int id = blockIdx.x * 4 + w;               // [0, 8192)
  int bh = id >> 10;                         // [0,8)
  int ksp = (id >> 8) & 3;                   // key split [0,4)
  int ntile = id & 255;
  int n0 = ntile * 16;
  int quad = lane >> 4, nl = lane & 15;
  int v = nl;

  short8 aq = {};
  if (quad == 0) aq = *(const short8*)(Qbf + ((size_t)bh * 4096 + n0 + nl) * 8);

  short8 ones8;
#pragma unroll
  for (int i = 0; i < 8; ++i) ones8[i] = (short)0x3F80;  // bf16 1.0

  const ushort_t* Krows = Kbf + ((size_t)bh * 4096 + ksp * 1024) * 8;
  const ushort_t* Vbase = VtTp + ((size_t)bh * 8 + (v < 8 ? v : 0)) * 4096
                          + ksp * 1024 + quad * 8;
  ushort_t* Pw = Plds + w * 2 * 640;
  uint_t* Pw32 = (uint_t*)Pw;

  float4v acc = {};

#define QKEXP(mi)                                                              \
  {                                                                            \
    int m0 = (mi) * 32;                                                        \
    short8 bk0 = {}, bk1 = {};                                                 \
    if (quad == 0) {                                                           \
      bk0 = *(const short8*)(Krows + (size_t)(m0 + nl) * 8);                   \
      bk1 = *(const short8*)(Krows + (size_t)(m0 + 16 + nl) * 8);              \
    }                                                                          \
    float4v s0 = __builtin_amdgcn_mfma_f32_16x16x32_bf16(                      \
        aq, bk0, (float4v){0.f, 0.f, 0.f, 0.f}, 0, 0, 0);                      \
    float4v s1 = __builtin_amdgcn_mfma_f32_16x16x32_bf16(                      \
        aq, bk1, (float4v){0.f, 0.f, 0.f, 0.f}, 0, 0, 0);                      \
    uint_t* Pt32 = Pw32 + ((mi) & 1) * 320;                                    \
    _Pragma("unroll") for (int r = 0; r < 4; ++r) {                            \
      float e0 = __builtin_amdgcn_exp2f(s0[r]);                                \
      float e1 = __builtin_amdgcn_exp2f(s1[r]);                                \
      Pt32[(quad * 4 + r) * 20 + nl] = pk2bf(e0, e1);                          \
    }                                                                          \
  }

#define PV(mi)                                                                 \
  {                                                                            \
    const ushort_t* Pt = Pw + ((mi) & 1) * 640;                                \
    short8 a2 = *(const short8*)(Pt + nl * 40 + quad * 8);                     \
    short8 b2;                                                                 \
    if (v < 8)       b2 = *(const short8*)(Vbase + (mi) * 32);                 \
    else if (v == 8) b2 = ones8;                                               \
    else             b2 = (short8){};                                          \
    acc = __builtin_amdgcn_mfma_f32_16x16x32_bf16(a2, b2, acc, 0, 0, 0);       \
  }

  QKEXP(0)
#pragma unroll 2
  for (int mi = 1; mi < 32; ++mi) {
    QKEXP(mi)
    PV(mi - 1)
  }
  PV(31)
#undef QKEXP
#undef PV

  // acc: O-partial[n][v] at col=v=nl, row=quad*4+r; col 8 = partial row-sum l.
#pragma unroll
  for (int r = 0; r < 4; ++r) {
    int rowg = bh * 4096 + n0 + quad * 4 + r;    // [0, 32768)
    if (v < 8)       pacc[((size_t)rowg * 4 + ksp) * 8 + v] = acc[r];
    else if (v == 8) pl[(size_t)rowg * 4 + ksp] = acc[r];
  }
}

// Merge 4 key-split partials, divide by l, write attn with the reference's
// faithful-reshape: attn[b][h*8 + (n>>9)][(n&511)*8 + c]. Thread per (row,c).
__global__ __launch_bounds__(256) void kMerge(const float* __restrict__ pacc,
                                              const float* __restrict__ pl,
                                              float* __restrict__ attn) {
  int idx = blockIdx.x * 256 + threadIdx.x;  // [0, 262144)
  int row = idx >> 3;
  int c = idx & 7;
  float l = 0.f, a = 0.f;
#pragma unroll
  for (int s = 0; s < 4; ++s) {
    l += pl[(size_t)row * 4 + s];
    a += pacc[((size_t)row * 4 + s) * 8 + c];
  }
  int b = row >> 14;
  int h = (row >> 12) & 3;
  int n = row & 4095;
  attn[((size_t)(b * 32 + h * 8 + (n >> 9)) << 12) + ((n & 511) * 8 + c)] = a / l;
}

// 1x1x1 conv + bias -> out channels 32..63. 2 out-ch per thread, 512 blocks.
__global__ __launch_bounds__(256) void kOut(const float* __restrict__ attn,
                                            const float* __restrict__ w_out,
                                            const float* __restrict__ b_out,
                                            float* __restrict__ out) {
  int idx = blockIdx.x * 256 + threadIdx.x;  // [0, 131072)
  int s = idx & 4095;
  int b = (idx >> 12) & 1;
  int cp = idx >> 13;                        // [0,16) co-pair, block-uniform
  float a[32];
#pragma unroll
  for (int ci = 0; ci < 32; ++ci) a[ci] = attn[(size_t)(b * 32 + ci) * 4096 + s];
#pragma unroll
  for (int oo = 0; oo < 2; ++oo) {
    int co = cp * 2 + oo;
    float r = b_out[co];
#pragma unroll
    for (int ci = 0; ci < 32; ++ci) r = fmaf(w_out[co * 32 + ci], a[ci], r);
    out[(size_t)(b * 64 + 32 + co) * 4096 + s] = r;
  }
}

extern "C" void kernel_launch(void* const* d_in, const int* in_sizes, int n_in,
                              void* d_out, int out_size, void* d_ws, size_t ws_size,
                              hipStream_t stream) {
  const float* x      = (const float*)d_in[0];
  const float* w_init = (const float*)d_in[1];
  const float* w_qkv  = (const float*)d_in[2];
  const float* w_out  = (const float*)d_in[3];
  const float* b_out  = (const float*)d_in[4];
  float* out = (float*)d_out;

  // ws: wT 110592 f | Qbf 262144 u16 | Kbf 262144 u16 | VtTp 262144 u16 |
  //     attn 262144 f | pacc 1048576 f | pl 131072 f   (~7.4 MB)
  float* wT = (float*)d_ws;
  ushort_t* Qbf = (ushort_t*)(wT + 110592);
  ushort_t* Kbf = Qbf + 262144;
  ushort_t* VtTp = Kbf + 262144;
  float* attn = (float*)(VtTp + 262144);
  float* pacc = attn + 262144;
  float* pl = pacc + 1048576;

  kW    <<<432,  256, 0, stream>>>(w_init, w_qkv, wT);
  kConv <<<1024, 256, 0, stream>>>(x, wT, out, Qbf, Kbf, VtTp);
  kAttn <<<2048, 256, 0, stream>>>(Qbf, Kbf, VtTp, pacc, pl);
  kMerge<<<1024, 256, 0, stream>>>(pacc, pl, attn);
  kOut  <<<512,  256, 0, stream>>>(attn, w_out, b_out, out);
}

// Round 6
// 142.337 us; speedup vs baseline: 1.4433x; 1.0909x over previous
//
#include <hip/hip_runtime.h>

// ---------------------------------------------------------------------------
// x(2,32,16,16,16), w_init(32,32,27), w_qkv(96,32,27), w_out(32,32), b_out(32).
// out(2,64,4096). heads=4, dk_h=dv_h=8, N=4096, scale=8^-0.5 (folded into the
// q-weights together with log2e; softmax uses exp2).
// Conv = 27 tap-shifted bf16 MFMA GEMMs (K=32 = ic). Attention via bf16 MFMA,
// key-split 4x, software-pipelined P LDS round-trip.
// ---------------------------------------------------------------------------

typedef short short8 __attribute__((ext_vector_type(8)));
typedef float float4v __attribute__((ext_vector_type(4)));
typedef unsigned short ushort_t;
typedef unsigned int uint_t;

__device__ inline ushort_t f2bf(float x) {   // fp32 -> bf16 RNE
  uint_t u = __builtin_bit_cast(uint_t, x);
  u += 0x7FFFu + ((u >> 16) & 1u);
  return (ushort_t)(u >> 16);
}

__device__ inline uint_t pk2bf(float lo, float hi) {  // packed bf16x2 dword
  return (uint_t)f2bf(lo) | ((uint_t)f2bf(hi) << 16);
}

// Fused prep. Blocks 0..431: build A-fragment weight layout
//   wA[otile(8)][tap(27)][lane(64)][j(8)] bf16, where o = otile*16 + (lane&15),
//   ic = (lane>>4)*8 + j. o: 0..31 init, 32..63 q (xQS), 64..95 k, 96..127 v.
// Blocks 432..463: transpose x (b,ic,s) fp32 -> xb[b][s][ic] bf16 via LDS.
__global__ __launch_bounds__(256) void kPrep(const float* __restrict__ w_init,
                                             const float* __restrict__ w_qkv,
                                             const float* __restrict__ x,
                                             ushort_t* __restrict__ wA,
                                             ushort_t* __restrict__ xb) {
  __shared__ float xsf[256 * 34];   // 34 KB (34-pad: 8B-aligned rows, no conflicts)
  int t = threadIdx.x;
  int bx = blockIdx.x;
  if (bx < 432) {
    int idx = bx * 256 + t;          // [0, 110592)
    int j = idx & 7;
    int lane = (idx >> 3) & 63;
    int tap = (idx >> 9) % 27;
    int otile = idx / (27 * 512);
    int o = otile * 16 + (lane & 15);
    int ic = (lane >> 4) * 8 + j;
    const float QS = 0.35355339059327373f * 1.4426950408889634f;
    float v;
    if (o < 32) v = w_init[(o * 32 + ic) * 27 + tap];
    else        v = w_qkv[((o - 32) * 32 + ic) * 27 + tap];
    if (o >= 32 && o < 64) v *= QS;
    wA[idx] = f2bf(v);
  } else {
    int bxx = bx - 432;              // [0,32) = b*16 + z
    int z = bxx & 15, b = bxx >> 4;
#pragma unroll
    for (int ic = 0; ic < 32; ++ic)
      xsf[t * 34 + ic] = x[((size_t)(b * 32 + ic) * 16 + z) * 256 + t];
    __syncthreads();
#pragma unroll
    for (int r = 0; r < 4; ++r) {
      int slot = r * 256 + t;        // [0,1024)
      int s = slot >> 2;
      int icg = slot & 3;
      ushort_t tmp[8];
#pragma unroll
      for (int jj = 0; jj < 8; ++jj) tmp[jj] = f2bf(xsf[s * 34 + icg * 8 + jj]);
      *(short8*)(xb + ((size_t)(b * 16 + z) * 256 + s) * 32 + icg * 8) = *(short8*)tmp;
    }
  }
}

// MFMA conv: block=(b,z), grid 32, 4 waves. Stage 3 wrapped z-planes of
// xb[s][ic] bf16 in LDS (48 KB). Wave w owns y-rows w*4..w*4+3 and ALL 8
// o-tiles. Per tap: 8 coalesced A-frag global loads (vmcnt domain) +
// 4 ds_read_b128 B-frags + 32 mfma. acc[8][4] in 128 VGPRs.
__global__ __launch_bounds__(256, 1) void kConv(const ushort_t* __restrict__ xb,
                                                const ushort_t* __restrict__ wA,
                                                float* __restrict__ out,
                                                ushort_t* __restrict__ Qbf,
                                                ushort_t* __restrict__ Kbf,
                                                ushort_t* __restrict__ VtTp) {
  __shared__ ushort_t xs[3 * 256 * 32];   // 48 KB: [plane][s=y*16+x][ic]
  int tid = threadIdx.x;
  int w = tid >> 6, lane = tid & 63;
  int quad = lane >> 4, nl = lane & 15;
  int bx = blockIdx.x;              // [0,32) = b*16 + z
  int z = bx & 15, b = bx >> 4;

  // stage 3 wrapped z-planes (each 16 KB contiguous in xb)
#pragma unroll
  for (int j = 0; j < 12; ++j) {
    int idx = j * 256 + tid;        // ushort8 slot [0,3072)
    int p = idx >> 10;              // plane
    int rem = idx & 1023;
    int zr = (z + p + 15) & 15;
    *(short8*)(xs + p * 8192 + rem * 8) =
        *(const short8*)(xb + (size_t)(b * 16 + zr) * 8192 + rem * 8);
  }
  __syncthreads();

  float4v acc[8][4];
#pragma unroll
  for (int ot = 0; ot < 8; ++ot)
#pragma unroll
    for (int st = 0; st < 4; ++st) acc[ot][st] = (float4v){0.f, 0.f, 0.f, 0.f};

  int y0 = w * 4;
  for (int tap = 0; tap < 27; ++tap) {
    int kz = tap / 9, kyx = tap % 9;
    int ky = kyx / 3, kx = kyx % 3;
    short8 afrag[8];
#pragma unroll
    for (int ot = 0; ot < 8; ++ot)
      afrag[ot] = *(const short8*)(wA + ((size_t)(ot * 27 + tap) * 64 + lane) * 8);
    int xsh = (nl + kx + 15) & 15;
#pragma unroll
    for (int st = 0; st < 4; ++st) {
      int yy = (y0 + st + ky + 15) & 15;
      short8 bfrag = *(const short8*)(xs + ((kz * 256) + yy * 16 + xsh) * 32 + quad * 8);
#pragma unroll
      for (int ot = 0; ot < 8; ++ot)
        acc[ot][st] = __builtin_amdgcn_mfma_f32_16x16x32_bf16(afrag[ot], bfrag, acc[ot][st], 0, 0, 0);
    }
  }

  // Epilogue. C layout: col = nl (spatial x), row = quad*4 + r (o in tile).
#pragma unroll
  for (int st = 0; st < 4; ++st) {
    int y = y0 + st;
    int s = z * 256 + y * 16 + nl;
#pragma unroll
    for (int ot = 0; ot < 2; ++ot)
#pragma unroll
      for (int r = 0; r < 4; ++r) {
        int o = ot * 16 + quad * 4 + r;
        out[(size_t)(b * 64 + o) * 4096 + s] = acc[ot][st][r];
      }
#pragma unroll
    for (int ot = 2; ot < 4; ++ot)
#pragma unroll
      for (int r = 0; r < 4; ++r) {
        int q = (ot - 2) * 16 + quad * 4 + r;
        int h = q >> 3, c = q & 7;
        Qbf[((size_t)(b * 4 + h) * 4096 + s) * 8 + c] = f2bf(acc[ot][st][r]);
      }
#pragma unroll
    for (int ot = 4; ot < 6; ++ot)
#pragma unroll
      for (int r = 0; r < 4; ++r) {
        int k = (ot - 4) * 16 + quad * 4 + r;
        int h = k >> 3, c = k & 7;
        Kbf[((size_t)(b * 4 + h) * 4096 + s) * 8 + c] = f2bf(acc[ot][st][r]);
      }
    int mperm = 2 * nl + (y & 1);   // k'-interleave matching kAttn's P order
#pragma unroll
    for (int ot = 6; ot < 8; ++ot)
#pragma unroll
      for (int r = 0; r < 4; ++r) {
        int v = (ot - 6) * 16 + quad * 4 + r;
        int h = v >> 3, c = v & 7;
        VtTp[((size_t)(b * 4 + h) * 8 + c) * 4096 + (size_t)(s & ~31) + mperm] =
            f2bf(acc[ot][st][r]);
      }
  }
}

// MFMA attention, key-split 4x. One wave = 16 query rows x 1024 keys.
// Grid = 2048 blocks x 4 waves = 8192 waves (8 blocks/CU).
// Pipeline: chunk i's QK->exp->packed P write goes to LDS buffer (i&1) while
// the PV mfma consumes buffer ((i-1)&1). P is stored k-interleaved so each
// lane writes ONE packed dword; V was pre-permuted identically.
// PV B-operand: V ch 0..7, ones at v=8 (row-sum l for free), zeros above.
__global__ __launch_bounds__(256) void kAttn(const ushort_t* __restrict__ Qbf,
                                             const ushort_t* __restrict__ Kbf,
                                             const ushort_t* __restrict__ VtTp,
                                             float* __restrict__ pacc,
                                             float* __restrict__ pl) {
  __shared__ ushort_t Plds[4 * 2 * 16 * 40];  // 4 waves x 2 bufs x 16 rows x 40
  int tid = threadIdx.x;
  int w = tid >> 6, lane = tid & 63;
  int id = blockIdx.x * 4 + w;               // [0, 8192)
  int bh = id >> 10;                         // [0,8)
  int ksp = (id >> 8) & 3;                   // key split [0,4)
  int ntile = id & 255;
  int n0 = ntile * 16;
  int quad = lane >> 4, nl = lane & 15;
  int v = nl;

  short8 aq = {};
  if (quad == 0) aq = *(const short8*)(Qbf + ((size_t)bh * 4096 + n0 + nl) * 8);

  short8 ones8;
#pragma unroll
  for (int i = 0; i < 8; ++i) ones8[i] = (short)0x3F80;  // bf16 1.0

  const ushort_t* Krows = Kbf + ((size_t)bh * 4096 + ksp * 1024) * 8;
  const ushort_t* Vbase = VtTp + ((size_t)bh * 8 + (v < 8 ? v : 0)) * 4096
                          + ksp * 1024 + quad * 8;
  ushort_t* Pw = Plds + w * 2 * 640;
  uint_t* Pw32 = (uint_t*)Pw;

  float4v acc = {};

#define QKEXP(mi)                                                              \
  {                                                                            \
    int m0 = (mi) * 32;                                                        \
    short8 bk0 = {}, bk1 = {};                                                 \
    if (quad == 0) {                                                           \
      bk0 = *(const short8*)(Krows + (size_t)(m0 + nl) * 8);                   \
      bk1 = *(const short8*)(Krows + (size_t)(m0 + 16 + nl) * 8);              \
    }                                                                          \
    float4v s0 = __builtin_amdgcn_mfma_f32_16x16x32_bf16(                      \
        aq, bk0, (float4v){0.f, 0.f, 0.f, 0.f}, 0, 0, 0);                      \
    float4v s1 = __builtin_amdgcn_mfma_f32_16x16x32_bf16(                      \
        aq, bk1, (float4v){0.f, 0.f, 0.f, 0.f}, 0, 0, 0);                      \
    uint_t* Pt32 = Pw32 + ((mi) & 1) * 320;                                    \
    _Pragma("unroll") for (int r = 0; r < 4; ++r) {                            \
      float e0 = __builtin_amdgcn_exp2f(s0[r]);                                \
      float e1 = __builtin_amdgcn_exp2f(s1[r]);                                \
      Pt32[(quad * 4 + r) * 20 + nl] = pk2bf(e0, e1);                          \
    }                                                                          \
  }

#define PV(mi)                                                                 \
  {                                                                            \
    const ushort_t* Pt = Pw + ((mi) & 1) * 640;                                \
    short8 a2 = *(const short8*)(Pt + nl * 40 + quad * 8);                     \
    short8 b2;                                                                 \
    if (v < 8)       b2 = *(const short8*)(Vbase + (mi) * 32);                 \
    else if (v == 8) b2 = ones8;                                               \
    else             b2 = (short8){};                                          \
    acc = __builtin_amdgcn_mfma_f32_16x16x32_bf16(a2, b2, acc, 0, 0, 0);       \
  }

  QKEXP(0)
#pragma unroll 2
  for (int mi = 1; mi < 32; ++mi) {
    QKEXP(mi)
    PV(mi - 1)
  }
  PV(31)
#undef QKEXP
#undef PV

  // acc: O-partial[n][v] at col=v=nl, row=quad*4+r; col 8 = partial row-sum l.
#pragma unroll
  for (int r = 0; r < 4; ++r) {
    int rowg = bh * 4096 + n0 + quad * 4 + r;    // [0, 32768)
    if (v < 8)       pacc[((size_t)rowg * 4 + ksp) * 8 + v] = acc[r];
    else if (v == 8) pl[(size_t)rowg * 4 + ksp] = acc[r];
  }
}

// Merge 4 key-split partials, divide by l, write attn with the reference's
// faithful-reshape: attn[b][h*8 + (n>>9)][(n&511)*8 + c]. Thread per (row,c).
__global__ __launch_bounds__(256) void kMerge(const float* __restrict__ pacc,
                                              const float* __restrict__ pl,
                                              float* __restrict__ attn) {
  int idx = blockIdx.x * 256 + threadIdx.x;  // [0, 262144)
  int row = idx >> 3;
  int c = idx & 7;
  float l = 0.f, a = 0.f;
#pragma unroll
  for (int s = 0; s < 4; ++s) {
    l += pl[(size_t)row * 4 + s];
    a += pacc[((size_t)row * 4 + s) * 8 + c];
  }
  int b = row >> 14;
  int h = (row >> 12) & 3;
  int n = row & 4095;
  attn[((size_t)(b * 32 + h * 8 + (n >> 9)) << 12) + ((n & 511) * 8 + c)] = a / l;
}

// 1x1x1 conv + bias -> out channels 32..63. 2 out-ch per thread, 512 blocks.
__global__ __launch_bounds__(256) void kOut(const float* __restrict__ attn,
                                            const float* __restrict__ w_out,
                                            const float* __restrict__ b_out,
                                            float* __restrict__ out) {
  int idx = blockIdx.x * 256 + threadIdx.x;  // [0, 131072)
  int s = idx & 4095;
  int b = (idx >> 12) & 1;
  int cp = idx >> 13;                        // [0,16) co-pair, block-uniform
  float a[32];
#pragma unroll
  for (int ci = 0; ci < 32; ++ci) a[ci] = attn[(size_t)(b * 32 + ci) * 4096 + s];
#pragma unroll
  for (int oo = 0; oo < 2; ++oo) {
    int co = cp * 2 + oo;
    float r = b_out[co];
#pragma unroll
    for (int ci = 0; ci < 32; ++ci) r = fmaf(w_out[co * 32 + ci], a[ci], r);
    out[(size_t)(b * 64 + 32 + co) * 4096 + s] = r;
  }
}

extern "C" void kernel_launch(void* const* d_in, const int* in_sizes, int n_in,
                              void* d_out, int out_size, void* d_ws, size_t ws_size,
                              hipStream_t stream) {
  const float* x      = (const float*)d_in[0];
  const float* w_init = (const float*)d_in[1];
  const float* w_qkv  = (const float*)d_in[2];
  const float* w_out  = (const float*)d_in[3];
  const float* b_out  = (const float*)d_in[4];
  float* out = (float*)d_out;

  // ws: wA 110592 u16 | xb 262144 u16 | Qbf/Kbf/VtTp 262144 u16 each |
  //     attn 262144 f | pacc 1048576 f | pl 131072 f   (~7.7 MB)
  ushort_t* wA  = (ushort_t*)d_ws;
  ushort_t* xb  = wA + 110592;
  ushort_t* Qbf = xb + 262144;
  ushort_t* Kbf = Qbf + 262144;
  ushort_t* VtTp = Kbf + 262144;
  float* attn = (float*)(VtTp + 262144);
  float* pacc = attn + 262144;
  float* pl = pacc + 1048576;

  kPrep <<<464,  256, 0, stream>>>(w_init, w_qkv, x, wA, xb);
  kConv <<<32,   256, 0, stream>>>(xb, wA, out, Qbf, Kbf, VtTp);
  kAttn <<<2048, 256, 0, stream>>>(Qbf, Kbf, VtTp, pacc, pl);
  kMerge<<<1024, 256, 0, stream>>>(pacc, pl, attn);
  kOut  <<<512,  256, 0, stream>>>(attn, w_out, b_out, out);
}

// Round 7
// 124.032 us; speedup vs baseline: 1.6564x; 1.1476x over previous
//
#include <hip/hip_runtime.h>

// ---------------------------------------------------------------------------
// x(2,32,16,16,16), w_init(32,32,27), w_qkv(96,32,27), w_out(32,32), b_out(32).
// out(2,64,4096). heads=4, dk_h=dv_h=8, N=4096, scale=8^-0.5 (folded into the
// q-weights together with log2e; softmax uses exp2).
// Conv = 27 tap-shifted bf16 MFMA GEMMs (K=32 = ic). Attention via bf16 MFMA,
// key-split 4x, software-pipelined P LDS round-trip, v_cvt_pk_bf16_f32 pack.
// ---------------------------------------------------------------------------

typedef short short8 __attribute__((ext_vector_type(8)));
typedef float float4v __attribute__((ext_vector_type(4)));
typedef unsigned short ushort_t;
typedef unsigned int uint_t;

__device__ inline ushort_t f2bf(float x) {   // fp32 -> bf16 RNE (scalar path)
  uint_t u = __builtin_bit_cast(uint_t, x);
  u += 0x7FFFu + ((u >> 16) & 1u);
  return (ushort_t)(u >> 16);
}

__device__ inline uint_t cvtpk(float lo, float hi) {  // packed bf16x2, RNE, 1 inst
  uint_t r;
  asm("v_cvt_pk_bf16_f32 %0, %1, %2" : "=v"(r) : "v"(lo), "v"(hi));
  return r;
}

// Fused prep. Blocks 0..431: build A-fragment weight layout
//   wA[otile(8)][tap(27)][lane(64)][j(8)] bf16, where o = otile*16 + (lane&15),
//   ic = (lane>>4)*8 + j. o: 0..31 init, 32..63 q (xQS), 64..95 k, 96..127 v.
// Blocks 432..463: transpose x (b,ic,s) fp32 -> xb[b][s][ic] bf16 via LDS.
__global__ __launch_bounds__(256) void kPrep(const float* __restrict__ w_init,
                                             const float* __restrict__ w_qkv,
                                             const float* __restrict__ x,
                                             ushort_t* __restrict__ wA,
                                             ushort_t* __restrict__ xb) {
  __shared__ float xsf[256 * 34];   // 34 KB (34-pad: 8B-aligned rows, no conflicts)
  int t = threadIdx.x;
  int bx = blockIdx.x;
  if (bx < 432) {
    int idx = bx * 256 + t;          // [0, 110592)
    int j = idx & 7;
    int lane = (idx >> 3) & 63;
    int tap = (idx >> 9) % 27;
    int otile = idx / (27 * 512);
    int o = otile * 16 + (lane & 15);
    int ic = (lane >> 4) * 8 + j;
    const float QS = 0.35355339059327373f * 1.4426950408889634f;
    float v;
    if (o < 32) v = w_init[(o * 32 + ic) * 27 + tap];
    else        v = w_qkv[((o - 32) * 32 + ic) * 27 + tap];
    if (o >= 32 && o < 64) v *= QS;
    wA[idx] = f2bf(v);
  } else {
    int bxx = bx - 432;              // [0,32) = b*16 + z
    int z = bxx & 15, b = bxx >> 4;
#pragma unroll
    for (int ic = 0; ic < 32; ++ic)
      xsf[t * 34 + ic] = x[((size_t)(b * 32 + ic) * 16 + z) * 256 + t];
    __syncthreads();
#pragma unroll
    for (int r = 0; r < 4; ++r) {
      int slot = r * 256 + t;        // [0,1024)
      int s = slot >> 2;
      int icg = slot & 3;
      ushort_t tmp[8];
#pragma unroll
      for (int jj = 0; jj < 8; ++jj) tmp[jj] = f2bf(xsf[s * 34 + icg * 8 + jj]);
      *(short8*)(xb + ((size_t)(b * 16 + z) * 256 + s) * 32 + icg * 8) = *(short8*)tmp;
    }
  }
}

// MFMA conv: block=(b,z,oq), grid 128 (b*64 + z*4 + oq), 4 waves. Stage 3
// wrapped z-planes of xb[s][ic] bf16 in LDS (48 KB). Wave w owns y-rows
// w*4..w*4+3 and o-tiles oq*2, oq*2+1. Per tap: 2 coalesced A-frag global
// loads + 4 ds_read_b128 B-frags + 8 mfma. acc[2][4] = 32 VGPRs.
__global__ __launch_bounds__(256, 1) void kConv(const ushort_t* __restrict__ xb,
                                                const ushort_t* __restrict__ wA,
                                                float* __restrict__ out,
                                                ushort_t* __restrict__ Qbf,
                                                ushort_t* __restrict__ Kbf,
                                                ushort_t* __restrict__ VtTp) {
  __shared__ ushort_t xs[3 * 256 * 32];   // 48 KB: [plane][s=y*16+x][ic]
  int tid = threadIdx.x;
  int w = tid >> 6, lane = tid & 63;
  int quad = lane >> 4, nl = lane & 15;
  int bx = blockIdx.x;              // [0,128) = b*64 + z*4 + oq
  int oq = bx & 3;
  int z = (bx >> 2) & 15;
  int b = bx >> 6;

  // stage 3 wrapped z-planes (each 16 KB contiguous in xb)
#pragma unroll
  for (int j = 0; j < 12; ++j) {
    int idx = j * 256 + tid;        // ushort8 slot [0,3072)
    int p = idx >> 10;              // plane
    int rem = idx & 1023;
    int zr = (z + p + 15) & 15;
    *(short8*)(xs + p * 8192 + rem * 8) =
        *(const short8*)(xb + (size_t)(b * 16 + zr) * 8192 + rem * 8);
  }
  __syncthreads();

  float4v acc[2][4];
#pragma unroll
  for (int ot = 0; ot < 2; ++ot)
#pragma unroll
    for (int st = 0; st < 4; ++st) acc[ot][st] = (float4v){0.f, 0.f, 0.f, 0.f};

  int y0 = w * 4;
  for (int tap = 0; tap < 27; ++tap) {
    int kz = tap / 9, kyx = tap % 9;
    int ky = kyx / 3, kx = kyx % 3;
    short8 afrag[2];
#pragma unroll
    for (int ot = 0; ot < 2; ++ot)
      afrag[ot] = *(const short8*)(wA + ((size_t)((oq * 2 + ot) * 27 + tap) * 64 + lane) * 8);
    int xsh = (nl + kx + 15) & 15;
#pragma unroll
    for (int st = 0; st < 4; ++st) {
      int yy = (y0 + st + ky + 15) & 15;
      short8 bfrag = *(const short8*)(xs + ((kz * 256) + yy * 16 + xsh) * 32 + quad * 8);
#pragma unroll
      for (int ot = 0; ot < 2; ++ot)
        acc[ot][st] = __builtin_amdgcn_mfma_f32_16x16x32_bf16(afrag[ot], bfrag, acc[ot][st], 0, 0, 0);
    }
  }

  // Epilogue. C layout: col = nl (spatial x), row = quad*4 + r (o in tile).
#pragma unroll
  for (int st = 0; st < 4; ++st) {
    int y = y0 + st;
    int s = z * 256 + y * 16 + nl;
    int mperm = 2 * nl + (y & 1);   // k'-interleave matching kAttn's P order
#pragma unroll
    for (int ot = 0; ot < 2; ++ot) {
      int otg = oq * 2 + ot;
#pragma unroll
      for (int r = 0; r < 4; ++r) {
        float val = acc[ot][st][r];
        int oo = (otg & 1) * 16 + quad * 4 + r;   // index within 32-ch group
        if (otg < 2) {
          out[(size_t)(b * 64 + oo) * 4096 + s] = val;
        } else if (otg < 4) {
          int h = oo >> 3, c = oo & 7;
          Qbf[((size_t)(b * 4 + h) * 4096 + s) * 8 + c] = f2bf(val);
        } else if (otg < 6) {
          int h = oo >> 3, c = oo & 7;
          Kbf[((size_t)(b * 4 + h) * 4096 + s) * 8 + c] = f2bf(val);
        } else {
          int h = oo >> 3, c = oo & 7;
          VtTp[((size_t)(b * 4 + h) * 8 + c) * 4096 + (size_t)(s & ~31) + mperm] = f2bf(val);
        }
      }
    }
  }
}

// MFMA attention, key-split 4x. One wave = 16 query rows x 1024 keys.
// Grid = 2048 blocks x 4 waves = 8192 waves (8 blocks/CU).
// Pipeline: chunk i's QK->exp->packed P write goes to LDS buffer (i&1) while
// the PV mfma consumes buffer ((i-1)&1). P is stored k-interleaved so each
// lane writes ONE packed dword (v_cvt_pk_bf16_f32); V pre-permuted identically.
// PV B-operand: V ch 0..7, ones at v=8 (row-sum l for free), zeros above.
__global__ __launch_bounds__(256) void kAttn(const ushort_t* __restrict__ Qbf,
                                             const ushort_t* __restrict__ Kbf,
                                             const ushort_t* __restrict__ VtTp,
                                             float* __restrict__ pacc,
                                             float* __restrict__ pl) {
  __shared__ ushort_t Plds[4 * 2 * 16 * 40];  // 4 waves x 2 bufs x 16 rows x 40
  int tid = threadIdx.x;
  int w = tid >> 6, lane = tid & 63;
  int id = blockIdx.x * 4 + w;               // [0, 8192)
  int bh = id >> 10;                         // [0,8)
  int ksp = (id >> 8) & 3;                   // key split [0,4)
  int ntile = id & 255;
  int n0 = ntile * 16;
  int quad = lane >> 4, nl = lane & 15;
  int v = nl;

  short8 aq = {};
  if (quad == 0) aq = *(const short8*)(Qbf + ((size_t)bh * 4096 + n0 + nl) * 8);

  short8 ones8;
#pragma unroll
  for (int i = 0; i < 8; ++i) ones8[i] = (short)0x3F80;  // bf16 1.0

  const ushort_t* Krows = Kbf + ((size_t)bh * 4096 + ksp * 1024) * 8;
  const ushort_t* Vbase = VtTp + ((size_t)bh * 8 + (v < 8 ? v : 0)) * 4096
                          + ksp * 1024 + quad * 8;
  ushort_t* Pw = Plds + w * 2 * 640;
  uint_t* Pw32 = (uint_t*)Pw;

  float4v acc = {};

#define QKEXP(mi)                                                              \
  {                                                                            \
    int m0 = (mi) * 32;                                                        \
    short8 bk0 = {}, bk1 = {};                                                 \
    if (quad == 0) {                                                           \
      bk0 = *(const short8*)(Krows + (size_t)(m0 + nl) * 8);                   \
      bk1 = *(const short8*)(Krows + (size_t)(m0 + 16 + nl) * 8);              \
    }                                                                          \
    float4v s0 = __builtin_amdgcn_mfma_f32_16x16x32_bf16(                      \
        aq, bk0, (float4v){0.f, 0.f, 0.f, 0.f}, 0, 0, 0);                      \
    float4v s1 = __builtin_amdgcn_mfma_f32_16x16x32_bf16(                      \
        aq, bk1, (float4v){0.f, 0.f, 0.f, 0.f}, 0, 0, 0);                      \
    uint_t* Pt32 = Pw32 + ((mi) & 1) * 320;                                    \
    _Pragma("unroll") for (int r = 0; r < 4; ++r) {                            \
      float e0 = __builtin_amdgcn_exp2f(s0[r]);                                \
      float e1 = __builtin_amdgcn_exp2f(s1[r]);                                \
      Pt32[(quad * 4 + r) * 20 + nl] = cvtpk(e0, e1);                          \
    }                                                                          \
  }

#define PV(mi)                                                                 \
  {                                                                            \
    const ushort_t* Pt = Pw + ((mi) & 1) * 640;                                \
    short8 a2 = *(const short8*)(Pt + nl * 40 + quad * 8);                     \
    short8 b2;                                                                 \
    if (v < 8)       b2 = *(const short8*)(Vbase + (mi) * 32);                 \
    else if (v == 8) b2 = ones8;                                               \
    else             b2 = (short8){};                                          \
    acc = __builtin_amdgcn_mfma_f32_16x16x32_bf16(a2, b2, acc, 0, 0, 0);       \
  }

  QKEXP(0)
#pragma unroll 2
  for (int mi = 1; mi < 32; ++mi) {
    QKEXP(mi)
    PV(mi - 1)
  }
  PV(31)
#undef QKEXP
#undef PV

  // acc: O-partial[n][v] at col=v=nl, row=quad*4+r; col 8 = partial row-sum l.
#pragma unroll
  for (int r = 0; r < 4; ++r) {
    int rowg = bh * 4096 + n0 + quad * 4 + r;    // [0, 32768)
    if (v < 8)       pacc[((size_t)rowg * 4 + ksp) * 8 + v] = acc[r];
    else if (v == 8) pl[(size_t)rowg * 4 + ksp] = acc[r];
  }
}

// Merge 4 key-split partials, divide by l, write attn with the reference's
// faithful-reshape: attn[b][h*8 + (n>>9)][(n&511)*8 + c]. Thread per (row,c).
__global__ __launch_bounds__(256) void kMerge(const float* __restrict__ pacc,
                                              const float* __restrict__ pl,
                                              float* __restrict__ attn) {
  int idx = blockIdx.x * 256 + threadIdx.x;  // [0, 262144)
  int row = idx >> 3;
  int c = idx & 7;
  float l = 0.f, a = 0.f;
#pragma unroll
  for (int s = 0; s < 4; ++s) {
    l += pl[(size_t)row * 4 + s];
    a += pacc[((size_t)row * 4 + s) * 8 + c];
  }
  int b = row >> 14;
  int h = (row >> 12) & 3;
  int n = row & 4095;
  attn[((size_t)(b * 32 + h * 8 + (n >> 9)) << 12) + ((n & 511) * 8 + c)] = a / l;
}

// 1x1x1 conv + bias -> out channels 32..63. 2 out-ch per thread, 512 blocks.
__global__ __launch_bounds__(256) void kOut(const float* __restrict__ attn,
                                            const float* __restrict__ w_out,
                                            const float* __restrict__ b_out,
                                            float* __restrict__ out) {
  int idx = blockIdx.x * 256 + threadIdx.x;  // [0, 131072)
  int s = idx & 4095;
  int b = (idx >> 12) & 1;
  int cp = idx >> 13;                        // [0,16) co-pair, block-uniform
  float a[32];
#pragma unroll
  for (int ci = 0; ci < 32; ++ci) a[ci] = attn[(size_t)(b * 32 + ci) * 4096 + s];
#pragma unroll
  for (int oo = 0; oo < 2; ++oo) {
    int co = cp * 2 + oo;
    float r = b_out[co];
#pragma unroll
    for (int ci = 0; ci < 32; ++ci) r = fmaf(w_out[co * 32 + ci], a[ci], r);
    out[(size_t)(b * 64 + 32 + co) * 4096 + s] = r;
  }
}

extern "C" void kernel_launch(void* const* d_in, const int* in_sizes, int n_in,
                              void* d_out, int out_size, void* d_ws, size_t ws_size,
                              hipStream_t stream) {
  const float* x      = (const float*)d_in[0];
  const float* w_init = (const float*)d_in[1];
  const float* w_qkv  = (const float*)d_in[2];
  const float* w_out  = (const float*)d_in[3];
  const float* b_out  = (const float*)d_in[4];
  float* out = (float*)d_out;

  // ws: wA 110592 u16 | xb 262144 u16 | Qbf/Kbf/VtTp 262144 u16 each |
  //     attn 262144 f | pacc 1048576 f | pl 131072 f   (~7.7 MB)
  ushort_t* wA  = (ushort_t*)d_ws;
  ushort_t* xb  = wA + 110592;
  ushort_t* Qbf = xb + 262144;
  ushort_t* Kbf = Qbf + 262144;
  ushort_t* VtTp = Kbf + 262144;
  float* attn = (float*)(VtTp + 262144);
  float* pacc = attn + 262144;
  float* pl = pacc + 1048576;

  kPrep <<<464,  256, 0, stream>>>(w_init, w_qkv, x, wA, xb);
  kConv <<<128,  256, 0, stream>>>(xb, wA, out, Qbf, Kbf, VtTp);
  kAttn <<<2048, 256, 0, stream>>>(Qbf, Kbf, VtTp, pacc, pl);
  kMerge<<<1024, 256, 0, stream>>>(pacc, pl, attn);
  kOut  <<<512,  256, 0, stream>>>(attn, w_out, b_out, out);
}

// Round 8
// 109.687 us; speedup vs baseline: 1.8730x; 1.1308x over previous
//
#include <hip/hip_runtime.h>

// ---------------------------------------------------------------------------
// x(2,32,16,16,16), w_init(32,32,27), w_qkv(96,32,27), w_out(32,32), b_out(32).
// out(2,64,4096). heads=4, dk_h=dv_h=8, N=4096, scale=8^-0.5 (folded into the
// q-weights together with log2e; softmax uses exp2).
// Conv = 27 tap-shifted bf16 MFMA GEMMs (K=32 = ic). Attention via bf16 MFMA:
// 2 n-tiles/wave, full-wave K loads + dual Q A-variants (k-octet 0/1),
// read-before-write software pipeline on the P LDS round-trip.
// ---------------------------------------------------------------------------

typedef short short8 __attribute__((ext_vector_type(8)));
typedef float float4v __attribute__((ext_vector_type(4)));
typedef unsigned short ushort_t;
typedef unsigned int uint_t;

__device__ inline ushort_t f2bf(float x) {   // fp32 -> bf16 RNE (scalar path)
  uint_t u = __builtin_bit_cast(uint_t, x);
  u += 0x7FFFu + ((u >> 16) & 1u);
  return (ushort_t)(u >> 16);
}

__device__ inline uint_t cvtpk(float lo, float hi) {  // packed bf16x2, RNE, 1 inst
  uint_t r;
  asm("v_cvt_pk_bf16_f32 %0, %1, %2" : "=v"(r) : "v"(lo), "v"(hi));
  return r;
}

// Fused prep. Blocks 0..431: build A-fragment weight layout
//   wA[otile(8)][tap(27)][lane(64)][j(8)] bf16, where o = otile*16 + (lane&15),
//   ic = (lane>>4)*8 + j. o: 0..31 init, 32..63 q (xQS), 64..95 k, 96..127 v.
// Blocks 432..463: transpose x (b,ic,s) fp32 -> xb[b][s][ic] bf16 via LDS.
__global__ __launch_bounds__(256) void kPrep(const float* __restrict__ w_init,
                                             const float* __restrict__ w_qkv,
                                             const float* __restrict__ x,
                                             ushort_t* __restrict__ wA,
                                             ushort_t* __restrict__ xb) {
  __shared__ float xsf[256 * 34];   // 34 KB (34-pad: 8B-aligned rows, no conflicts)
  int t = threadIdx.x;
  int bx = blockIdx.x;
  if (bx < 432) {
    int idx = bx * 256 + t;          // [0, 110592)
    int j = idx & 7;
    int lane = (idx >> 3) & 63;
    int tap = (idx >> 9) % 27;
    int otile = idx / (27 * 512);
    int o = otile * 16 + (lane & 15);
    int ic = (lane >> 4) * 8 + j;
    const float QS = 0.35355339059327373f * 1.4426950408889634f;
    float v;
    if (o < 32) v = w_init[(o * 32 + ic) * 27 + tap];
    else        v = w_qkv[((o - 32) * 32 + ic) * 27 + tap];
    if (o >= 32 && o < 64) v *= QS;
    wA[idx] = f2bf(v);
  } else {
    int bxx = bx - 432;              // [0,32) = b*16 + z
    int z = bxx & 15, b = bxx >> 4;
#pragma unroll
    for (int ic = 0; ic < 32; ++ic)
      xsf[t * 34 + ic] = x[((size_t)(b * 32 + ic) * 16 + z) * 256 + t];
    __syncthreads();
#pragma unroll
    for (int r = 0; r < 4; ++r) {
      int slot = r * 256 + t;        // [0,1024)
      int s = slot >> 2;
      int icg = slot & 3;
      ushort_t tmp[8];
#pragma unroll
      for (int jj = 0; jj < 8; ++jj) tmp[jj] = f2bf(xsf[s * 34 + icg * 8 + jj]);
      *(short8*)(xb + ((size_t)(b * 16 + z) * 256 + s) * 32 + icg * 8) = *(short8*)tmp;
    }
  }
}

// MFMA conv: block=(b,z,oq), grid 128 (b*64 + z*4 + oq), 4 waves. Stage 3
// wrapped z-planes of xb[s][ic] bf16 in LDS (48 KB). Wave w owns y-rows
// w*4..w*4+3 and o-tiles oq*2, oq*2+1. Per tap: 2 coalesced A-frag global
// loads + 4 ds_read_b128 B-frags + 8 mfma. acc[2][4] = 32 VGPRs.
__global__ __launch_bounds__(256, 1) void kConv(const ushort_t* __restrict__ xb,
                                                const ushort_t* __restrict__ wA,
                                                float* __restrict__ out,
                                                ushort_t* __restrict__ Qbf,
                                                ushort_t* __restrict__ Kbf,
                                                ushort_t* __restrict__ VtTp) {
  __shared__ ushort_t xs[3 * 256 * 32];   // 48 KB: [plane][s=y*16+x][ic]
  int tid = threadIdx.x;
  int w = tid >> 6, lane = tid & 63;
  int quad = lane >> 4, nl = lane & 15;
  int bx = blockIdx.x;              // [0,128) = b*64 + z*4 + oq
  int oq = bx & 3;
  int z = (bx >> 2) & 15;
  int b = bx >> 6;

  // stage 3 wrapped z-planes (each 16 KB contiguous in xb)
#pragma unroll
  for (int j = 0; j < 12; ++j) {
    int idx = j * 256 + tid;        // ushort8 slot [0,3072)
    int p = idx >> 10;              // plane
    int rem = idx & 1023;
    int zr = (z + p + 15) & 15;
    *(short8*)(xs + p * 8192 + rem * 8) =
        *(const short8*)(xb + (size_t)(b * 16 + zr) * 8192 + rem * 8);
  }
  __syncthreads();

  float4v acc[2][4];
#pragma unroll
  for (int ot = 0; ot < 2; ++ot)
#pragma unroll
    for (int st = 0; st < 4; ++st) acc[ot][st] = (float4v){0.f, 0.f, 0.f, 0.f};

  int y0 = w * 4;
  for (int tap = 0; tap < 27; ++tap) {
    int kz = tap / 9, kyx = tap % 9;
    int ky = kyx / 3, kx = kyx % 3;
    short8 afrag[2];
#pragma unroll
    for (int ot = 0; ot < 2; ++ot)
      afrag[ot] = *(const short8*)(wA + ((size_t)((oq * 2 + ot) * 27 + tap) * 64 + lane) * 8);
    int xsh = (nl + kx + 15) & 15;
#pragma unroll
    for (int st = 0; st < 4; ++st) {
      int yy = (y0 + st + ky + 15) & 15;
      short8 bfrag = *(const short8*)(xs + ((kz * 256) + yy * 16 + xsh) * 32 + quad * 8);
#pragma unroll
      for (int ot = 0; ot < 2; ++ot)
        acc[ot][st] = __builtin_amdgcn_mfma_f32_16x16x32_bf16(afrag[ot], bfrag, acc[ot][st], 0, 0, 0);
    }
  }

  // Epilogue. C layout: col = nl (spatial x), row = quad*4 + r (o in tile).
#pragma unroll
  for (int st = 0; st < 4; ++st) {
    int y = y0 + st;
    int s = z * 256 + y * 16 + nl;
    int mperm = 2 * nl + (y & 1);   // k'-interleave matching kAttn's P order
#pragma unroll
    for (int ot = 0; ot < 2; ++ot) {
      int otg = oq * 2 + ot;
#pragma unroll
      for (int r = 0; r < 4; ++r) {
        float val = acc[ot][st][r];
        int oo = (otg & 1) * 16 + quad * 4 + r;   // index within 32-ch group
        if (otg < 2) {
          out[(size_t)(b * 64 + oo) * 4096 + s] = val;
        } else if (otg < 4) {
          int h = oo >> 3, c = oo & 7;
          Qbf[((size_t)(b * 4 + h) * 4096 + s) * 8 + c] = f2bf(val);
        } else if (otg < 6) {
          int h = oo >> 3, c = oo & 7;
          Kbf[((size_t)(b * 4 + h) * 4096 + s) * 8 + c] = f2bf(val);
        } else {
          int h = oo >> 3, c = oo & 7;
          VtTp[((size_t)(b * 4 + h) * 8 + c) * 4096 + (size_t)(s & ~31) + mperm] = f2bf(val);
        }
      }
    }
  }
}

// MFMA attention, key-split 4x, 2 n-tiles (32 query rows) per wave.
// Grid = 1024 blocks x 4 waves = 4096 waves (16 waves/CU).
// K loaded FULL-WAVE (lane -> row m0+(lane&31)); quads 2-3 duplicate rows but
// their k-octets multiply Q-fragment zeros. Two Q A-variants (Q in k-octet 0
// resp. 1) extract keys 0..15 / 16..31 from the one load. P round-trip is
// read-BEFORE-write pipelined: the ds_read of chunk i-1 issues before chunk
// i's QK/exp/writes, so its latency hides under ~250cy of independent work.
// PV B-operand: V ch 0..7, ones at v=8 (row-sum l for free), zeros above.
__global__ __launch_bounds__(256) void kAttn(const ushort_t* __restrict__ Qbf,
                                             const ushort_t* __restrict__ Kbf,
                                             const ushort_t* __restrict__ VtTp,
                                             float* __restrict__ pacc,
                                             float* __restrict__ pl) {
  __shared__ ushort_t Plds[4 * 2 * 2 * 640];  // [wave][tile][buf][16*40]
  int tid = threadIdx.x;
  int w = tid >> 6, lane = tid & 63;
  int id = blockIdx.x * 4 + w;               // [0, 4096)
  int bh = id >> 9;                          // [0,8)
  int ksp = (id >> 7) & 3;                   // key split [0,4)
  int ntile = id & 127;                      // [0,128)
  int n0 = ntile * 32;
  int quad = lane >> 4, nl = lane & 15;
  int l31 = lane & 31;
  int v = nl;

  short8 z8 = {};
  // Q rows for both tiles, loaded by ALL lanes (quads duplicate -> broadcast)
  short8 q0f = *(const short8*)(Qbf + ((size_t)bh * 4096 + n0 + nl) * 8);
  short8 q1f = *(const short8*)(Qbf + ((size_t)bh * 4096 + n0 + 16 + nl) * 8);
  short8 aq0A = (quad == 0) ? q0f : z8;   // tile0, Q in k-octet 0 -> keys 0..15
  short8 aq0B = (quad == 1) ? q0f : z8;   // tile0, Q in k-octet 1 -> keys 16..31
  short8 aq1A = (quad == 0) ? q1f : z8;
  short8 aq1B = (quad == 1) ? q1f : z8;

  short8 ones8;
#pragma unroll
  for (int i = 0; i < 8; ++i) ones8[i] = (short)0x3F80;  // bf16 1.0

  const ushort_t* Krows = Kbf + ((size_t)bh * 4096 + ksp * 1024) * 8;
  const ushort_t* Vrow = VtTp + ((size_t)bh * 8 + (v < 8 ? v : 0)) * 4096
                         + ksp * 1024 + quad * 8;
  ushort_t* P0 = Plds + (w * 2 + 0) * 2 * 640;
  ushort_t* P1 = Plds + (w * 2 + 1) * 2 * 640;

  float4v acc0 = {}, acc1 = {};

#define QKEXP(mi, bkr)                                                         \
  {                                                                            \
    float4v s00 = __builtin_amdgcn_mfma_f32_16x16x32_bf16(                     \
        aq0A, bkr, (float4v){0.f, 0.f, 0.f, 0.f}, 0, 0, 0);                    \
    float4v s01 = __builtin_amdgcn_mfma_f32_16x16x32_bf16(                     \
        aq0B, bkr, (float4v){0.f, 0.f, 0.f, 0.f}, 0, 0, 0);                    \
    float4v s10 = __builtin_amdgcn_mfma_f32_16x16x32_bf16(                     \
        aq1A, bkr, (float4v){0.f, 0.f, 0.f, 0.f}, 0, 0, 0);                    \
    float4v s11 = __builtin_amdgcn_mfma_f32_16x16x32_bf16(                     \
        aq1B, bkr, (float4v){0.f, 0.f, 0.f, 0.f}, 0, 0, 0);                    \
    uint_t* Pt0 = (uint_t*)(P0 + ((mi) & 1) * 640);                            \
    uint_t* Pt1 = (uint_t*)(P1 + ((mi) & 1) * 640);                            \
    _Pragma("unroll") for (int r = 0; r < 4; ++r) {                            \
      Pt0[(quad * 4 + r) * 20 + nl] =                                          \
          cvtpk(__builtin_amdgcn_exp2f(s00[r]), __builtin_amdgcn_exp2f(s01[r]));\
      Pt1[(quad * 4 + r) * 20 + nl] =                                          \
          cvtpk(__builtin_amdgcn_exp2f(s10[r]), __builtin_amdgcn_exp2f(s11[r]));\
    }                                                                          \
  }

#define PVSTEP(a2, bv, accv)                                                   \
  {                                                                            \
    short8 b2 = (v < 8) ? (bv) : ((v == 8) ? ones8 : z8);                      \
    accv = __builtin_amdgcn_mfma_f32_16x16x32_bf16(a2, b2, accv, 0, 0, 0);     \
  }

  short8 bk = *(const short8*)(Krows + (size_t)l31 * 8);       // chunk 0
  QKEXP(0, bk)
  bk = *(const short8*)(Krows + (size_t)(32 + l31) * 8);       // chunk 1

#pragma unroll 2
  for (int mi = 1; mi < 32; ++mi) {
    int pb = ((mi - 1) & 1) * 640;
    // read P(mi-1) FIRST: its latency hides under this chunk's QK/exp/writes
    short8 a20 = *(const short8*)(P0 + pb + nl * 40 + quad * 8);
    short8 a21 = *(const short8*)(P1 + pb + nl * 40 + quad * 8);
    short8 bv = *(const short8*)(Vrow + (mi - 1) * 32);
    QKEXP(mi, bk)
    int nxt = ((mi + 1) & 31) * 32;                            // clamped wrap
    bk = *(const short8*)(Krows + (size_t)(nxt + l31) * 8);
    PVSTEP(a20, bv, acc0)
    PVSTEP(a21, bv, acc1)
  }
  {
    int pb = 640;                                              // (31&1)*640
    short8 a20 = *(const short8*)(P0 + pb + nl * 40 + quad * 8);
    short8 a21 = *(const short8*)(P1 + pb + nl * 40 + quad * 8);
    short8 bv = *(const short8*)(Vrow + 31 * 32);
    PVSTEP(a20, bv, acc0)
    PVSTEP(a21, bv, acc1)
  }
#undef QKEXP
#undef PVSTEP

  // acc: O-partial[n][v] at col=v=nl, row=quad*4+r; col 8 = partial row-sum l.
#pragma unroll
  for (int r = 0; r < 4; ++r) {
    int rq = quad * 4 + r;
    int rowg0 = bh * 4096 + n0 + rq;           // [0, 32768)
    int rowg1 = rowg0 + 16;
    if (v < 8) {
      pacc[((size_t)rowg0 * 4 + ksp) * 8 + v] = acc0[r];
      pacc[((size_t)rowg1 * 4 + ksp) * 8 + v] = acc1[r];
    } else if (v == 8) {
      pl[(size_t)rowg0 * 4 + ksp] = acc0[r];
      pl[(size_t)rowg1 * 4 + ksp] = acc1[r];
    }
  }
}

// Merge 4 key-split partials, divide by l, write attn with the reference's
// faithful-reshape: attn[b][h*8 + (n>>9)][(n&511)*8 + c]. Thread per (row,c).
__global__ __launch_bounds__(256) void kMerge(const float* __restrict__ pacc,
                                              const float* __restrict__ pl,
                                              float* __restrict__ attn) {
  int idx = blockIdx.x * 256 + threadIdx.x;  // [0, 262144)
  int row = idx >> 3;
  int c = idx & 7;
  float l = 0.f, a = 0.f;
#pragma unroll
  for (int s = 0; s < 4; ++s) {
    l += pl[(size_t)row * 4 + s];
    a += pacc[((size_t)row * 4 + s) * 8 + c];
  }
  int b = row >> 14;
  int h = (row >> 12) & 3;
  int n = row & 4095;
  attn[((size_t)(b * 32 + h * 8 + (n >> 9)) << 12) + ((n & 511) * 8 + c)] = a / l;
}

// 1x1x1 conv + bias -> out channels 32..63. 2 out-ch per thread, 512 blocks.
__global__ __launch_bounds__(256) void kOut(const float* __restrict__ attn,
                                            const float* __restrict__ w_out,
                                            const float* __restrict__ b_out,
                                            float* __restrict__ out) {
  int idx = blockIdx.x * 256 + threadIdx.x;  // [0, 131072)
  int s = idx & 4095;
  int b = (idx >> 12) & 1;
  int cp = idx >> 13;                        // [0,16) co-pair, block-uniform
  float a[32];
#pragma unroll
  for (int ci = 0; ci < 32; ++ci) a[ci] = attn[(size_t)(b * 32 + ci) * 4096 + s];
#pragma unroll
  for (int oo = 0; oo < 2; ++oo) {
    int co = cp * 2 + oo;
    float r = b_out[co];
#pragma unroll
    for (int ci = 0; ci < 32; ++ci) r = fmaf(w_out[co * 32 + ci], a[ci], r);
    out[(size_t)(b * 64 + 32 + co) * 4096 + s] = r;
  }
}

extern "C" void kernel_launch(void* const* d_in, const int* in_sizes, int n_in,
                              void* d_out, int out_size, void* d_ws, size_t ws_size,
                              hipStream_t stream) {
  const float* x      = (const float*)d_in[0];
  const float* w_init = (const float*)d_in[1];
  const float* w_qkv  = (const float*)d_in[2];
  const float* w_out  = (const float*)d_in[3];
  const float* b_out  = (const float*)d_in[4];
  float* out = (float*)d_out;

  // ws: wA 110592 u16 | xb 262144 u16 | Qbf/Kbf/VtTp 262144 u16 each |
  //     attn 262144 f | pacc 1048576 f | pl 131072 f   (~7.7 MB)
  ushort_t* wA  = (ushort_t*)d_ws;
  ushort_t* xb  = wA + 110592;
  ushort_t* Qbf = xb + 262144;
  ushort_t* Kbf = Qbf + 262144;
  ushort_t* VtTp = Kbf + 262144;
  float* attn = (float*)(VtTp + 262144);
  float* pacc = attn + 262144;
  float* pl = pacc + 1048576;

  kPrep <<<464,  256, 0, stream>>>(w_init, w_qkv, x, wA, xb);
  kConv <<<128,  256, 0, stream>>>(xb, wA, out, Qbf, Kbf, VtTp);
  kAttn <<<1024, 256, 0, stream>>>(Qbf, Kbf, VtTp, pacc, pl);
  kMerge<<<1024, 256, 0, stream>>>(pacc, pl, attn);
  kOut  <<<512,  256, 0, stream>>>(attn, w_out, b_out, out);
}

// Round 9
// 109.537 us; speedup vs baseline: 1.8756x; 1.0014x over previous
//
#include <hip/hip_runtime.h>

// ---------------------------------------------------------------------------
// x(2,32,16,16,16), w_init(32,32,27), w_qkv(96,32,27), w_out(32,32), b_out(32).
// out(2,64,4096). heads=4, dk_h=dv_h=8, N=4096, scale=8^-0.5 (folded into the
// q-weights together with log2e; softmax uses exp2).
// Conv = 27 tap-shifted bf16 MFMA GEMMs (K=32 = ic). Attention via bf16 MFMA:
// key-split 8x (8192 waves = 8/SIMD), 2 n-tiles/wave, full-wave K loads +
// dual Q A-variants, read-before-write P pipeline. Merge fused into kOut.
// ---------------------------------------------------------------------------

typedef short short8 __attribute__((ext_vector_type(8)));
typedef float float4v __attribute__((ext_vector_type(4)));
typedef unsigned short ushort_t;
typedef unsigned int uint_t;

__device__ inline ushort_t f2bf(float x) {   // fp32 -> bf16 RNE (scalar path)
  uint_t u = __builtin_bit_cast(uint_t, x);
  u += 0x7FFFu + ((u >> 16) & 1u);
  return (ushort_t)(u >> 16);
}

__device__ inline uint_t cvtpk(float lo, float hi) {  // packed bf16x2, RNE, 1 inst
  uint_t r;
  asm("v_cvt_pk_bf16_f32 %0, %1, %2" : "=v"(r) : "v"(lo), "v"(hi));
  return r;
}

// Fused prep. Blocks 0..431: build A-fragment weight layout
//   wA[otile(8)][tap(27)][lane(64)][j(8)] bf16, o = otile*16 + (lane&15),
//   ic = (lane>>4)*8 + j. o: 0..31 init, 32..63 q (xQS), 64..95 k, 96..127 v.
// Blocks 432..463: transpose x (b,ic,s) fp32 -> xb[b][s][ic] bf16 via LDS.
__global__ __launch_bounds__(256) void kPrep(const float* __restrict__ w_init,
                                             const float* __restrict__ w_qkv,
                                             const float* __restrict__ x,
                                             ushort_t* __restrict__ wA,
                                             ushort_t* __restrict__ xb) {
  __shared__ float xsf[256 * 34];   // 34 KB (34-pad: 8B-aligned rows, no conflicts)
  int t = threadIdx.x;
  int bx = blockIdx.x;
  if (bx < 432) {
    int idx = bx * 256 + t;          // [0, 110592)
    int j = idx & 7;
    int lane = (idx >> 3) & 63;
    int tap = (idx >> 9) % 27;
    int otile = idx / (27 * 512);
    int o = otile * 16 + (lane & 15);
    int ic = (lane >> 4) * 8 + j;
    const float QS = 0.35355339059327373f * 1.4426950408889634f;
    float v;
    if (o < 32) v = w_init[(o * 32 + ic) * 27 + tap];
    else        v = w_qkv[((o - 32) * 32 + ic) * 27 + tap];
    if (o >= 32 && o < 64) v *= QS;
    wA[idx] = f2bf(v);
  } else {
    int bxx = bx - 432;              // [0,32) = b*16 + z
    int z = bxx & 15, b = bxx >> 4;
#pragma unroll
    for (int ic = 0; ic < 32; ++ic)
      xsf[t * 34 + ic] = x[((size_t)(b * 32 + ic) * 16 + z) * 256 + t];
    __syncthreads();
#pragma unroll
    for (int r = 0; r < 4; ++r) {
      int slot = r * 256 + t;        // [0,1024)
      int s = slot >> 2;
      int icg = slot & 3;
      ushort_t tmp[8];
#pragma unroll
      for (int jj = 0; jj < 8; ++jj) tmp[jj] = f2bf(xsf[s * 34 + icg * 8 + jj]);
      *(short8*)(xb + ((size_t)(b * 16 + z) * 256 + s) * 32 + icg * 8) = *(short8*)tmp;
    }
  }
}

// MFMA conv: block=(b,z,oq), grid 128, 4 waves. Stage 3 wrapped z-planes of
// xb[s][ic] bf16 in LDS (48 KB). Wave w owns y-rows w*4..w*4+3 and o-tiles
// oq*2, oq*2+1. Per tap: 2 A-frag global loads + 4 ds_read_b128 + 8 mfma.
__global__ __launch_bounds__(256, 1) void kConv(const ushort_t* __restrict__ xb,
                                                const ushort_t* __restrict__ wA,
                                                float* __restrict__ out,
                                                ushort_t* __restrict__ Qbf,
                                                ushort_t* __restrict__ Kbf,
                                                ushort_t* __restrict__ VtTp) {
  __shared__ ushort_t xs[3 * 256 * 32];   // 48 KB: [plane][s=y*16+x][ic]
  int tid = threadIdx.x;
  int w = tid >> 6, lane = tid & 63;
  int quad = lane >> 4, nl = lane & 15;
  int bx = blockIdx.x;              // [0,128) = b*64 + z*4 + oq
  int oq = bx & 3;
  int z = (bx >> 2) & 15;
  int b = bx >> 6;

#pragma unroll
  for (int j = 0; j < 12; ++j) {
    int idx = j * 256 + tid;        // ushort8 slot [0,3072)
    int p = idx >> 10;              // plane
    int rem = idx & 1023;
    int zr = (z + p + 15) & 15;
    *(short8*)(xs + p * 8192 + rem * 8) =
        *(const short8*)(xb + (size_t)(b * 16 + zr) * 8192 + rem * 8);
  }
  __syncthreads();

  float4v acc[2][4];
#pragma unroll
  for (int ot = 0; ot < 2; ++ot)
#pragma unroll
    for (int st = 0; st < 4; ++st) acc[ot][st] = (float4v){0.f, 0.f, 0.f, 0.f};

  int y0 = w * 4;
  for (int tap = 0; tap < 27; ++tap) {
    int kz = tap / 9, kyx = tap % 9;
    int ky = kyx / 3, kx = kyx % 3;
    short8 afrag[2];
#pragma unroll
    for (int ot = 0; ot < 2; ++ot)
      afrag[ot] = *(const short8*)(wA + ((size_t)((oq * 2 + ot) * 27 + tap) * 64 + lane) * 8);
    int xsh = (nl + kx + 15) & 15;
#pragma unroll
    for (int st = 0; st < 4; ++st) {
      int yy = (y0 + st + ky + 15) & 15;
      short8 bfrag = *(const short8*)(xs + ((kz * 256) + yy * 16 + xsh) * 32 + quad * 8);
#pragma unroll
      for (int ot = 0; ot < 2; ++ot)
        acc[ot][st] = __builtin_amdgcn_mfma_f32_16x16x32_bf16(afrag[ot], bfrag, acc[ot][st], 0, 0, 0);
    }
  }

  // Epilogue. C layout: col = nl (spatial x), row = quad*4 + r (o in tile).
#pragma unroll
  for (int st = 0; st < 4; ++st) {
    int y = y0 + st;
    int s = z * 256 + y * 16 + nl;
    int mperm = 2 * nl + (y & 1);   // k'-interleave matching kAttn's P order
#pragma unroll
    for (int ot = 0; ot < 2; ++ot) {
      int otg = oq * 2 + ot;
#pragma unroll
      for (int r = 0; r < 4; ++r) {
        float val = acc[ot][st][r];
        int oo = (otg & 1) * 16 + quad * 4 + r;   // index within 32-ch group
        if (otg < 2) {
          out[(size_t)(b * 64 + oo) * 4096 + s] = val;
        } else if (otg < 4) {
          int h = oo >> 3, c = oo & 7;
          Qbf[((size_t)(b * 4 + h) * 4096 + s) * 8 + c] = f2bf(val);
        } else if (otg < 6) {
          int h = oo >> 3, c = oo & 7;
          Kbf[((size_t)(b * 4 + h) * 4096 + s) * 8 + c] = f2bf(val);
        } else {
          int h = oo >> 3, c = oo & 7;
          VtTp[((size_t)(b * 4 + h) * 8 + c) * 4096 + (size_t)(s & ~31) + mperm] = f2bf(val);
        }
      }
    }
  }
}

// MFMA attention, key-split 8x, 2 n-tiles (32 query rows) per wave.
// Grid = 2048 blocks x 4 waves = 8192 waves (8 waves/SIMD for latency hiding).
// Each wave: 32 rows x 512 keys = 16 chunks of 32 keys.
// K loaded FULL-WAVE (lane -> row m0+(lane&31)); two Q A-variants (Q in
// k-octet 0 resp. 1) extract keys 0..15 / 16..31 from the one load. P LDS
// round-trip is read-BEFORE-write pipelined. PV B-operand: V ch 0..7, ones
// at v=8 (row-sum l for free), zeros above.
__global__ __launch_bounds__(256) void kAttn(const ushort_t* __restrict__ Qbf,
                                             const ushort_t* __restrict__ Kbf,
                                             const ushort_t* __restrict__ VtTp,
                                             float* __restrict__ pacc,
                                             float* __restrict__ pl) {
  __shared__ ushort_t Plds[4 * 2 * 2 * 640];  // [wave][tile][buf][16*40]
  int tid = threadIdx.x;
  int w = tid >> 6, lane = tid & 63;
  int id = blockIdx.x * 4 + w;               // [0, 8192)
  int bh = id >> 10;                         // [0,8)
  int ksp = (id >> 7) & 7;                   // key split [0,8)
  int ntile = id & 127;                      // [0,128)
  int n0 = ntile * 32;
  int quad = lane >> 4, nl = lane & 15;
  int l31 = lane & 31;
  int v = nl;

  short8 z8 = {};
  short8 q0f = *(const short8*)(Qbf + ((size_t)bh * 4096 + n0 + nl) * 8);
  short8 q1f = *(const short8*)(Qbf + ((size_t)bh * 4096 + n0 + 16 + nl) * 8);
  short8 aq0A = (quad == 0) ? q0f : z8;   // tile0, Q in k-octet 0 -> keys 0..15
  short8 aq0B = (quad == 1) ? q0f : z8;   // tile0, Q in k-octet 1 -> keys 16..31
  short8 aq1A = (quad == 0) ? q1f : z8;
  short8 aq1B = (quad == 1) ? q1f : z8;

  short8 ones8;
#pragma unroll
  for (int i = 0; i < 8; ++i) ones8[i] = (short)0x3F80;  // bf16 1.0

  const ushort_t* Krows = Kbf + ((size_t)bh * 4096 + ksp * 512) * 8;
  const ushort_t* Vrow = VtTp + ((size_t)bh * 8 + (v < 8 ? v : 0)) * 4096
                         + ksp * 512 + quad * 8;
  ushort_t* P0 = Plds + (w * 2 + 0) * 2 * 640;
  ushort_t* P1 = Plds + (w * 2 + 1) * 2 * 640;

  float4v acc0 = {}, acc1 = {};

#define QKEXP(mi, bkr)                                                         \
  {                                                                            \
    float4v s00 = __builtin_amdgcn_mfma_f32_16x16x32_bf16(                     \
        aq0A, bkr, (float4v){0.f, 0.f, 0.f, 0.f}, 0, 0, 0);                    \
    float4v s01 = __builtin_amdgcn_mfma_f32_16x16x32_bf16(                     \
        aq0B, bkr, (float4v){0.f, 0.f, 0.f, 0.f}, 0, 0, 0);                    \
    float4v s10 = __builtin_amdgcn_mfma_f32_16x16x32_bf16(                     \
        aq1A, bkr, (float4v){0.f, 0.f, 0.f, 0.f}, 0, 0, 0);                    \
    float4v s11 = __builtin_amdgcn_mfma_f32_16x16x32_bf16(                     \
        aq1B, bkr, (float4v){0.f, 0.f, 0.f, 0.f}, 0, 0, 0);                    \
    uint_t* Pt0 = (uint_t*)(P0 + ((mi) & 1) * 640);                            \
    uint_t* Pt1 = (uint_t*)(P1 + ((mi) & 1) * 640);                            \
    _Pragma("unroll") for (int r = 0; r < 4; ++r) {                            \
      Pt0[(quad * 4 + r) * 20 + nl] =                                          \
          cvtpk(__builtin_amdgcn_exp2f(s00[r]), __builtin_amdgcn_exp2f(s01[r]));\
      Pt1[(quad * 4 + r) * 20 + nl] =                                          \
          cvtpk(__builtin_amdgcn_exp2f(s10[r]), __builtin_amdgcn_exp2f(s11[r]));\
    }                                                                          \
  }

#define PVSTEP(a2, bv, accv)                                                   \
  {                                                                            \
    short8 b2 = (v < 8) ? (bv) : ((v == 8) ? ones8 : z8);                      \
    accv = __builtin_amdgcn_mfma_f32_16x16x32_bf16(a2, b2, accv, 0, 0, 0);     \
  }

  short8 bk = *(const short8*)(Krows + (size_t)l31 * 8);       // chunk 0
  QKEXP(0, bk)
  bk = *(const short8*)(Krows + (size_t)(32 + l31) * 8);       // chunk 1

#pragma unroll 2
  for (int mi = 1; mi < 16; ++mi) {
    int pb = ((mi - 1) & 1) * 640;
    // read P(mi-1) FIRST: its latency hides under this chunk's QK/exp/writes
    short8 a20 = *(const short8*)(P0 + pb + nl * 40 + quad * 8);
    short8 a21 = *(const short8*)(P1 + pb + nl * 40 + quad * 8);
    short8 bv = *(const short8*)(Vrow + (mi - 1) * 32);
    QKEXP(mi, bk)
    int nxt = ((mi + 1) & 15) * 32;                            // wrap (dummy last)
    bk = *(const short8*)(Krows + (size_t)(nxt + l31) * 8);
    PVSTEP(a20, bv, acc0)
    PVSTEP(a21, bv, acc1)
  }
  {
    int pb = 640;                                              // (15&1)*640
    short8 a20 = *(const short8*)(P0 + pb + nl * 40 + quad * 8);
    short8 a21 = *(const short8*)(P1 + pb + nl * 40 + quad * 8);
    short8 bv = *(const short8*)(Vrow + 15 * 32);
    PVSTEP(a20, bv, acc0)
    PVSTEP(a21, bv, acc1)
  }
#undef QKEXP
#undef PVSTEP

  // acc: O-partial[n][v] at col=v=nl, row=quad*4+r; col 8 = partial row-sum l.
#pragma unroll
  for (int r = 0; r < 4; ++r) {
    int rq = quad * 4 + r;
    int rowg0 = bh * 4096 + n0 + rq;           // [0, 32768)
    int rowg1 = rowg0 + 16;
    if (v < 8) {
      pacc[((size_t)rowg0 * 8 + ksp) * 8 + v] = acc0[r];
      pacc[((size_t)rowg1 * 8 + ksp) * 8 + v] = acc1[r];
    } else if (v == 8) {
      pl[(size_t)rowg0 * 8 + ksp] = acc0[r];
      pl[(size_t)rowg1 * 8 + ksp] = acc1[r];
    }
  }
}

// Fused merge + 1x1x1 conv + bias -> out channels 32..63.
// Block = (b, 64-spatial tile); grid 128. Phase 1: merge the 8 key-split
// partials into LDS M[ci(32)][spl(64)] applying the reference's faithful
// reshape (attnR[ci][sp]: h=ci>>3, n=(ci&7)*512+(sp>>3), c=sp&7).
// Phase 2: 32->32 channel conv from LDS, coalesced stores.
__global__ __launch_bounds__(256) void kOut(const float* __restrict__ pacc,
                                            const float* __restrict__ pl,
                                            const float* __restrict__ w_out,
                                            const float* __restrict__ b_out,
                                            float* __restrict__ out) {
  __shared__ float M[32 * 64];   // 8 KB
  int bx = blockIdx.x;           // [0,128) = b*64 + spt
  int b = bx >> 6;
  int sp0 = (bx & 63) * 64;
  int t = threadIdx.x;

  // phase 1: thread t -> ci = t>>3, nsub = t&7 (covers sp = (sp0>>3+nsub)*8 + c)
  {
    int ci = t >> 3, nsub = t & 7;
    int h = ci >> 3, tt = ci & 7;
    int n = tt * 512 + (sp0 >> 3) + nsub;
    size_t row = (size_t)(b * 4 + h) * 4096 + n;
    float l = 0.f;
#pragma unroll
    for (int s = 0; s < 8; ++s) l += pl[row * 8 + s];
    float rl = 1.0f / l;
    float m[8];
#pragma unroll
    for (int c = 0; c < 8; ++c) m[c] = 0.f;
#pragma unroll
    for (int s = 0; s < 8; ++s) {
      const float4 p0 = *(const float4*)(pacc + (row * 8 + s) * 8);
      const float4 p1 = *(const float4*)(pacc + (row * 8 + s) * 8 + 4);
      m[0] += p0.x; m[1] += p0.y; m[2] += p0.z; m[3] += p0.w;
      m[4] += p1.x; m[5] += p1.y; m[6] += p1.z; m[7] += p1.w;
    }
    float4 o0 = {m[0] * rl, m[1] * rl, m[2] * rl, m[3] * rl};
    float4 o1 = {m[4] * rl, m[5] * rl, m[6] * rl, m[7] * rl};
    *(float4*)(M + ci * 64 + nsub * 8) = o0;
    *(float4*)(M + ci * 64 + nsub * 8 + 4) = o1;
  }
  __syncthreads();

  // phase 2: thread t -> spl = t&63, co-group t>>6 (8 channels each)
  {
    int spl = t & 63;
    int cog = t >> 6;              // wave-uniform
    float a[32];
#pragma unroll
    for (int ci = 0; ci < 32; ++ci) a[ci] = M[ci * 64 + spl];
#pragma unroll
    for (int oo = 0; oo < 8; ++oo) {
      int co = cog * 8 + oo;
      float r = b_out[co];
#pragma unroll
      for (int ci = 0; ci < 32; ++ci) r = fmaf(w_out[co * 32 + ci], a[ci], r);
      out[(size_t)(b * 64 + 32 + co) * 4096 + sp0 + spl] = r;
    }
  }
}

extern "C" void kernel_launch(void* const* d_in, const int* in_sizes, int n_in,
                              void* d_out, int out_size, void* d_ws, size_t ws_size,
                              hipStream_t stream) {
  const float* x      = (const float*)d_in[0];
  const float* w_init = (const float*)d_in[1];
  const float* w_qkv  = (const float*)d_in[2];
  const float* w_out  = (const float*)d_in[3];
  const float* b_out  = (const float*)d_in[4];
  float* out = (float*)d_out;

  // ws: wA 110592 u16 | xb/Qbf/Kbf/VtTp 262144 u16 each |
  //     pacc 2097152 f | pl 262144 f   (~11.7 MB)
  ushort_t* wA  = (ushort_t*)d_ws;
  ushort_t* xb  = wA + 110592;
  ushort_t* Qbf = xb + 262144;
  ushort_t* Kbf = Qbf + 262144;
  ushort_t* VtTp = Kbf + 262144;
  float* pacc = (float*)(VtTp + 262144);
  float* pl = pacc + 2097152;

  kPrep <<<464,  256, 0, stream>>>(w_init, w_qkv, x, wA, xb);
  kConv <<<128,  256, 0, stream>>>(xb, wA, out, Qbf, Kbf, VtTp);
  kAttn <<<2048, 256, 0, stream>>>(Qbf, Kbf, VtTp, pacc, pl);
  kOut  <<<128,  256, 0, stream>>>(pacc, pl, w_out, b_out, out);
}

// Round 11
// 104.623 us; speedup vs baseline: 1.9636x; 1.0470x over previous
//
#include <hip/hip_runtime.h>

// ---------------------------------------------------------------------------
// x(2,32,16,16,16), w_init(32,32,27), w_qkv(96,32,27), w_out(32,32), b_out(32).
// out(2,64,4096). heads=4, dk_h=dv_h=8, N=4096, scale=8^-0.5 (folded into the
// q-weights together with log2e; softmax uses exp2).
// Conv = 27 tap-shifted bf16 MFMA GEMMs (K=32 = ic), 256 blocks (full chip).
// Attention: bf16 MFMA, key-split KSP (4 or 8, chosen so the ws layout
// PROVABLY fits ws_size — round-8..10 used 11.76 MB unconditionally, which
// overran d_ws and corrupted neighboring allocations across timed replays),
// 2 n-tiles (32 rows)/wave, full-wave K loads + dual Q A-variants,
// read-before-write P pipeline. Merge fused into kOut.
// ---------------------------------------------------------------------------

typedef short short8 __attribute__((ext_vector_type(8)));
typedef float float4v __attribute__((ext_vector_type(4)));
typedef unsigned short ushort_t;
typedef unsigned int uint_t;

__device__ inline ushort_t f2bf(float x) {   // fp32 -> bf16 RNE (scalar path)
  uint_t u = __builtin_bit_cast(uint_t, x);
  u += 0x7FFFu + ((u >> 16) & 1u);
  return (ushort_t)(u >> 16);
}

__device__ inline uint_t cvtpk(float lo, float hi) {  // packed bf16x2, RNE, 1 inst
  uint_t r;
  asm("v_cvt_pk_bf16_f32 %0, %1, %2" : "=v"(r) : "v"(lo), "v"(hi));
  return r;
}

// Fused prep. Blocks 0..431: build A-fragment weight layout
//   wA[otile(8)][tap(27)][lane(64)][j(8)] bf16, o = otile*16 + (lane&15),
//   ic = (lane>>4)*8 + j. o: 0..31 init, 32..63 q (xQS), 64..95 k, 96..127 v.
// Blocks 432..463: transpose x (b,ic,s) fp32 -> xb[b][s][ic] bf16 via LDS.
__global__ __launch_bounds__(256) void kPrep(const float* __restrict__ w_init,
                                             const float* __restrict__ w_qkv,
                                             const float* __restrict__ x,
                                             ushort_t* __restrict__ wA,
                                             ushort_t* __restrict__ xb) {
  __shared__ float xsf[256 * 34];   // 34 KB (34-pad: 8B-aligned rows, no conflicts)
  int t = threadIdx.x;
  int bx = blockIdx.x;
  if (bx < 432) {
    int idx = bx * 256 + t;          // [0, 110592)
    int j = idx & 7;
    int lane = (idx >> 3) & 63;
    int tap = (idx >> 9) % 27;
    int otile = idx / (27 * 512);
    int o = otile * 16 + (lane & 15);
    int ic = (lane >> 4) * 8 + j;
    const float QS = 0.35355339059327373f * 1.4426950408889634f;
    float v;
    if (o < 32) v = w_init[(o * 32 + ic) * 27 + tap];
    else        v = w_qkv[((o - 32) * 32 + ic) * 27 + tap];
    if (o >= 32 && o < 64) v *= QS;
    wA[idx] = f2bf(v);
  } else {
    int bxx = bx - 432;              // [0,32) = b*16 + z
    int z = bxx & 15, b = bxx >> 4;
#pragma unroll
    for (int ic = 0; ic < 32; ++ic)
      xsf[t * 34 + ic] = x[((size_t)(b * 32 + ic) * 16 + z) * 256 + t];
    __syncthreads();
#pragma unroll
    for (int r = 0; r < 4; ++r) {
      int slot = r * 256 + t;        // [0,1024)
      int s = slot >> 2;
      int icg = slot & 3;
      ushort_t tmp[8];
#pragma unroll
      for (int jj = 0; jj < 8; ++jj) tmp[jj] = f2bf(xsf[s * 34 + icg * 8 + jj]);
      *(short8*)(xb + ((size_t)(b * 16 + z) * 256 + s) * 32 + icg * 8) = *(short8*)tmp;
    }
  }
}

// MFMA conv: block=(b,z,oq), grid 256 (full chip), 4 waves. Stage 3 wrapped
// z-planes of xb[s][ic] bf16 in LDS (48 KB). Wave w owns y-rows w*4..w*4+3
// and ONE o-tile (oq). Per tap: 1 A-frag global load + 4 ds_read_b128 + 4 mfma.
__global__ __launch_bounds__(256, 1) void kConv(const ushort_t* __restrict__ xb,
                                                const ushort_t* __restrict__ wA,
                                                float* __restrict__ out,
                                                ushort_t* __restrict__ Qbf,
                                                ushort_t* __restrict__ Kbf,
                                                ushort_t* __restrict__ VtTp) {
  __shared__ ushort_t xs[3 * 256 * 32];   // 48 KB: [plane][s=y*16+x][ic]
  int tid = threadIdx.x;
  int w = tid >> 6, lane = tid & 63;
  int quad = lane >> 4, nl = lane & 15;
  int bx = blockIdx.x;              // [0,256) = b*128 + z*8 + oq
  int oq = bx & 7;
  int z = (bx >> 3) & 15;
  int b = bx >> 7;

#pragma unroll
  for (int j = 0; j < 12; ++j) {
    int idx = j * 256 + tid;        // ushort8 slot [0,3072)
    int p = idx >> 10;              // plane
    int rem = idx & 1023;
    int zr = (z + p + 15) & 15;
    *(short8*)(xs + p * 8192 + rem * 8) =
        *(const short8*)(xb + (size_t)(b * 16 + zr) * 8192 + rem * 8);
  }
  __syncthreads();

  float4v acc[4];
#pragma unroll
  for (int st = 0; st < 4; ++st) acc[st] = (float4v){0.f, 0.f, 0.f, 0.f};

  int y0 = w * 4;
  for (int tap = 0; tap < 27; ++tap) {
    int kz = tap / 9, kyx = tap % 9;
    int ky = kyx / 3, kx = kyx % 3;
    short8 afrag = *(const short8*)(wA + ((size_t)(oq * 27 + tap) * 64 + lane) * 8);
    int xsh = (nl + kx + 15) & 15;
#pragma unroll
    for (int st = 0; st < 4; ++st) {
      int yy = (y0 + st + ky + 15) & 15;
      short8 bfrag = *(const short8*)(xs + ((kz * 256) + yy * 16 + xsh) * 32 + quad * 8);
      acc[st] = __builtin_amdgcn_mfma_f32_16x16x32_bf16(afrag, bfrag, acc[st], 0, 0, 0);
    }
  }

  // Epilogue. C layout: col = nl (spatial x), row = quad*4 + r (o in tile).
#pragma unroll
  for (int st = 0; st < 4; ++st) {
    int y = y0 + st;
    int s = z * 256 + y * 16 + nl;
    int mperm = 2 * nl + (y & 1);   // k'-interleave matching kAttn's P order
#pragma unroll
    for (int r = 0; r < 4; ++r) {
      float val = acc[st][r];
      int oo = (oq & 1) * 16 + quad * 4 + r;   // index within 32-ch group
      if (oq < 2) {
        out[(size_t)(b * 64 + oo) * 4096 + s] = val;
      } else if (oq < 4) {
        int h = oo >> 3, c = oo & 7;
        Qbf[((size_t)(b * 4 + h) * 4096 + s) * 8 + c] = f2bf(val);
      } else if (oq < 6) {
        int h = oo >> 3, c = oo & 7;
        Kbf[((size_t)(b * 4 + h) * 4096 + s) * 8 + c] = f2bf(val);
      } else {
        int h = oo >> 3, c = oo & 7;
        VtTp[((size_t)(b * 4 + h) * 8 + c) * 4096 + (size_t)(s & ~31) + mperm] = f2bf(val);
      }
    }
  }
}

// MFMA attention, key-split KSP, 2 n-tiles (32 query rows) per wave.
// Grid = 256*KSP blocks x 4 waves (KSP=4 -> 4096 waves, 4/SIMD — measured
// sufficient in r8/r9; 8/SIMD was neutral). Each wave: 32 rows x (4096/KSP)
// keys = 128/KSP chunks of 32. K loaded FULL-WAVE (lane -> row m0+(lane&31));
// two Q A-variants (k-octet 0 / 1) extract keys 0..15 / 16..31 from one load.
// P LDS round-trip read-BEFORE-write pipelined. PV B-operand: V ch 0..7,
// ones at v=8 (row-sum l for free), zeros above.
template <int KSP>
__global__ __launch_bounds__(256) void kAttn(const ushort_t* __restrict__ Qbf,
                                             const ushort_t* __restrict__ Kbf,
                                             const ushort_t* __restrict__ VtTp,
                                             float* __restrict__ pacc,
                                             float* __restrict__ pl) {
  const int NCH = 128 / KSP;                  // 32-key chunks per wave
  __shared__ ushort_t Plds[4 * 2 * 2 * 640];  // [wave][tile][buf][16*40]
  int tid = threadIdx.x;
  int w = tid >> 6, lane = tid & 63;
  int id = blockIdx.x * 4 + w;               // [0, 1024*KSP)
  int bh = id / (KSP * 128);                 // [0,8)
  int rem = id % (KSP * 128);
  int ksp = rem >> 7;                        // key split [0,KSP)
  int ntile = rem & 127;                     // [0,128)
  int n0 = ntile * 32;
  int quad = lane >> 4, nl = lane & 15;
  int l31 = lane & 31;
  int v = nl;

  short8 z8 = {};
  short8 q0f = *(const short8*)(Qbf + ((size_t)bh * 4096 + n0 + nl) * 8);
  short8 q1f = *(const short8*)(Qbf + ((size_t)bh * 4096 + n0 + 16 + nl) * 8);
  short8 aq0A = (quad == 0) ? q0f : z8;   // tile0, Q in k-octet 0 -> keys 0..15
  short8 aq0B = (quad == 1) ? q0f : z8;   // tile0, Q in k-octet 1 -> keys 16..31
  short8 aq1A = (quad == 0) ? q1f : z8;
  short8 aq1B = (quad == 1) ? q1f : z8;

  short8 ones8;
#pragma unroll
  for (int i = 0; i < 8; ++i) ones8[i] = (short)0x3F80;  // bf16 1.0

  const ushort_t* Krows = Kbf + ((size_t)bh * 4096 + ksp * (4096 / KSP)) * 8;
  const ushort_t* Vrow = VtTp + ((size_t)bh * 8 + (v < 8 ? v : 0)) * 4096
                         + ksp * (4096 / KSP) + quad * 8;
  ushort_t* P0 = Plds + (w * 2 + 0) * 2 * 640;
  ushort_t* P1 = Plds + (w * 2 + 1) * 2 * 640;

  float4v acc0 = {}, acc1 = {};

#define QKEXP(mi, bkr)                                                         \
  {                                                                            \
    float4v s00 = __builtin_amdgcn_mfma_f32_16x16x32_bf16(                     \
        aq0A, bkr, (float4v){0.f, 0.f, 0.f, 0.f}, 0, 0, 0);                    \
    float4v s01 = __builtin_amdgcn_mfma_f32_16x16x32_bf16(                     \
        aq0B, bkr, (float4v){0.f, 0.f, 0.f, 0.f}, 0, 0, 0);                    \
    float4v s10 = __builtin_amdgcn_mfma_f32_16x16x32_bf16(                     \
        aq1A, bkr, (float4v){0.f, 0.f, 0.f, 0.f}, 0, 0, 0);                    \
    float4v s11 = __builtin_amdgcn_mfma_f32_16x16x32_bf16(                     \
        aq1B, bkr, (float4v){0.f, 0.f, 0.f, 0.f}, 0, 0, 0);                    \
    uint_t* Pt0 = (uint_t*)(P0 + ((mi) & 1) * 640);                            \
    uint_t* Pt1 = (uint_t*)(P1 + ((mi) & 1) * 640);                            \
    _Pragma("unroll") for (int r = 0; r < 4; ++r) {                            \
      Pt0[(quad * 4 + r) * 20 + nl] =                                          \
          cvtpk(__builtin_amdgcn_exp2f(s00[r]), __builtin_amdgcn_exp2f(s01[r]));\
      Pt1[(quad * 4 + r) * 20 + nl] =                                          \
          cvtpk(__builtin_amdgcn_exp2f(s10[r]), __builtin_amdgcn_exp2f(s11[r]));\
    }                                                                          \
  }

#define PVSTEP(a2, bv, accv)                                                   \
  {                                                                            \
    short8 b2 = (v < 8) ? (bv) : ((v == 8) ? ones8 : z8);                      \
    accv = __builtin_amdgcn_mfma_f32_16x16x32_bf16(a2, b2, accv, 0, 0, 0);     \
  }

  short8 bk = *(const short8*)(Krows + (size_t)l31 * 8);       // chunk 0
  QKEXP(0, bk)
  bk = *(const short8*)(Krows + (size_t)(32 + l31) * 8);       // chunk 1

#pragma unroll 2
  for (int mi = 1; mi < NCH; ++mi) {
    int pb = ((mi - 1) & 1) * 640;
    // read P(mi-1) FIRST: its latency hides under this chunk's QK/exp/writes
    short8 a20 = *(const short8*)(P0 + pb + nl * 40 + quad * 8);
    short8 a21 = *(const short8*)(P1 + pb + nl * 40 + quad * 8);
    short8 bv = *(const short8*)(Vrow + (mi - 1) * 32);
    QKEXP(mi, bk)
    int nxt = ((mi + 1) & (NCH - 1)) * 32;                     // wrap (dummy last)
    bk = *(const short8*)(Krows + (size_t)(nxt + l31) * 8);
    PVSTEP(a20, bv, acc0)
    PVSTEP(a21, bv, acc1)
  }
  {
    int pb = ((NCH - 1) & 1) * 640;
    short8 a20 = *(const short8*)(P0 + pb + nl * 40 + quad * 8);
    short8 a21 = *(const short8*)(P1 + pb + nl * 40 + quad * 8);
    short8 bv = *(const short8*)(Vrow + (NCH - 1) * 32);
    PVSTEP(a20, bv, acc0)
    PVSTEP(a21, bv, acc1)
  }
#undef QKEXP
#undef PVSTEP

  // acc: O-partial[n][v] at col=v=nl, row=quad*4+r; col 8 = partial row-sum l.
#pragma unroll
  for (int r = 0; r < 4; ++r) {
    int rq = quad * 4 + r;
    int rowg0 = bh * 4096 + n0 + rq;           // [0, 32768)
    int rowg1 = rowg0 + 16;
    if (v < 8) {
      pacc[((size_t)rowg0 * KSP + ksp) * 8 + v] = acc0[r];
      pacc[((size_t)rowg1 * KSP + ksp) * 8 + v] = acc1[r];
    } else if (v == 8) {
      pl[(size_t)rowg0 * KSP + ksp] = acc0[r];
      pl[(size_t)rowg1 * KSP + ksp] = acc1[r];
    }
  }
}

// Fused merge + 1x1x1 conv + bias -> out channels 32..63.
// Block = (b, 64-spatial tile); grid 128. Phase 1: merge the KSP key-split
// partials into LDS M[ci(32)][spl(64)] applying the reference's faithful
// reshape (attnR[ci][sp]: h=ci>>3, n=(ci&7)*512+(sp>>3), c=sp&7).
// Phase 2: 32->32 channel conv from LDS, coalesced stores.
template <int KSP>
__global__ __launch_bounds__(256) void kOut(const float* __restrict__ pacc,
                                            const float* __restrict__ pl,
                                            const float* __restrict__ w_out,
                                            const float* __restrict__ b_out,
                                            float* __restrict__ out) {
  __shared__ float M[32 * 64];   // 8 KB
  int bx = blockIdx.x;           // [0,128) = b*64 + spt
  int b = bx >> 6;
  int sp0 = (bx & 63) * 64;
  int t = threadIdx.x;

  // phase 1: thread t -> ci = t>>3, nsub = t&7
  {
    int ci = t >> 3, nsub = t & 7;
    int h = ci >> 3, tt = ci & 7;
    int n = tt * 512 + (sp0 >> 3) + nsub;
    size_t row = (size_t)(b * 4 + h) * 4096 + n;
    float l = 0.f;
#pragma unroll
    for (int s = 0; s < KSP; ++s) l += pl[row * KSP + s];
    float rl = 1.0f / l;
    float m[8];
#pragma unroll
    for (int c = 0; c < 8; ++c) m[c] = 0.f;
#pragma unroll
    for (int s = 0; s < KSP; ++s) {
      const float4 p0 = *(const float4*)(pacc + (row * KSP + s) * 8);
      const float4 p1 = *(const float4*)(pacc + (row * KSP + s) * 8 + 4);
      m[0] += p0.x; m[1] += p0.y; m[2] += p0.z; m[3] += p0.w;
      m[4] += p1.x; m[5] += p1.y; m[6] += p1.z; m[7] += p1.w;
    }
    float4 o0 = {m[0] * rl, m[1] * rl, m[2] * rl, m[3] * rl};
    float4 o1 = {m[4] * rl, m[5] * rl, m[6] * rl, m[7] * rl};
    *(float4*)(M + ci * 64 + nsub * 8) = o0;
    *(float4*)(M + ci * 64 + nsub * 8 + 4) = o1;
  }
  __syncthreads();

  // phase 2: thread t -> spl = t&63, co-group t>>6 (8 channels each)
  {
    int spl = t & 63;
    int cog = t >> 6;              // wave-uniform
    float a[32];
#pragma unroll
    for (int ci = 0; ci < 32; ++ci) a[ci] = M[ci * 64 + spl];
#pragma unroll
    for (int oo = 0; oo < 8; ++oo) {
      int co = cog * 8 + oo;
      float r = b_out[co];
#pragma unroll
      for (int ci = 0; ci < 32; ++ci) r = fmaf(w_out[co * 32 + ci], a[ci], r);
      out[(size_t)(b * 64 + 32 + co) * 4096 + sp0 + spl] = r;
    }
  }
}

extern "C" void kernel_launch(void* const* d_in, const int* in_sizes, int n_in,
                              void* d_out, int out_size, void* d_ws, size_t ws_size,
                              hipStream_t stream) {
  const float* x      = (const float*)d_in[0];
  const float* w_init = (const float*)d_in[1];
  const float* w_qkv  = (const float*)d_in[2];
  const float* w_out  = (const float*)d_in[3];
  const float* b_out  = (const float*)d_in[4];
  float* out = (float*)d_out;

  // ws layout (bytes): wA 221184 | xb/Qbf/Kbf/VtTp 524288 each |
  //   pacc KSP*1048576 | pl KSP*131072.
  // KSP=8 needs 11,755,520 B; KSP=4 needs 7,036,928 B (proven safe: round-1's
  // 9.36 MB layout worked). Select by ws_size — rounds 8-10 used KSP=8
  // unconditionally and overran d_ws when ws_size < 11.76 MB.
  const size_t fixed = 221184 + 4 * 524288;
  int KSP = (ws_size >= fixed + (size_t)8 * (1048576 + 131072)) ? 8 : 4;

  ushort_t* wA  = (ushort_t*)d_ws;
  ushort_t* xb  = wA + 110592;
  ushort_t* Qbf = xb + 262144;
  ushort_t* Kbf = Qbf + 262144;
  ushort_t* VtTp = Kbf + 262144;
  float* pacc = (float*)(VtTp + 262144);
  float* pl = pacc + (size_t)KSP * 262144;

  kPrep <<<464, 256, 0, stream>>>(w_init, w_qkv, x, wA, xb);
  kConv <<<256, 256, 0, stream>>>(xb, wA, out, Qbf, Kbf, VtTp);
  if (KSP == 8) {
    kAttn<8><<<2048, 256, 0, stream>>>(Qbf, Kbf, VtTp, pacc, pl);
    kOut<8> <<<128, 256, 0, stream>>>(pacc, pl, w_out, b_out, out);
  } else {
    kAttn<4><<<1024, 256, 0, stream>>>(Qbf, Kbf, VtTp, pacc, pl);
    kOut<4> <<<128, 256, 0, stream>>>(pacc, pl, w_out, b_out, out);
  }
}

// Round 12
// 102.510 us; speedup vs baseline: 2.0041x; 1.0206x over previous
//
#include <hip/hip_runtime.h>

// ---------------------------------------------------------------------------
// x(2,32,16,16,16), w_init(32,32,27), w_qkv(96,32,27), w_out(32,32), b_out(32).
// out(2,64,4096). heads=4, dk_h=dv_h=8, N=4096, scale=8^-0.5 (folded into the
// q-weights together with log2e; softmax uses exp2).
// 3 kernels: kConv (self-staging: weights + x transpose fused in-block;
// 27 tap-shifted bf16 MFMA GEMMs, K=32=ic, kz-plane-wise), kAttn (bf16 MFMA,
// key-split KSP, 2 n-tiles/wave, full-wave K loads + dual Q A-variants,
// read-before-write P pipeline), kOut (merge + 1x1x1 conv fused).
// ---------------------------------------------------------------------------

typedef short short8 __attribute__((ext_vector_type(8)));
typedef float float4v __attribute__((ext_vector_type(4)));
typedef unsigned short ushort_t;
typedef unsigned int uint_t;

__device__ inline ushort_t f2bf(float x) {   // fp32 -> bf16 RNE (scalar path)
  uint_t u = __builtin_bit_cast(uint_t, x);
  u += 0x7FFFu + ((u >> 16) & 1u);
  return (ushort_t)(u >> 16);
}

__device__ inline uint_t cvtpk(float lo, float hi) {  // packed bf16x2, RNE, 1 inst
  uint_t r;
  asm("v_cvt_pk_bf16_f32 %0, %1, %2" : "=v"(r) : "v"(lo), "v"(hi));
  return r;
}

// MFMA conv, fully self-staging. Block=(b,z,oq), grid 256 (1 block/CU), 4 waves.
// Phase W: stage this block's CONTIGUOUS 54KB weight slice (o-major layout!)
//   into wl[tap(27)][lane(64)][j(8)] bf16: o = oq*16 + (lane&15),
//   ic = (lane>>4)*8 + j. q-tiles (oq 2,3) pre-scaled by QS.
// Phase X (per kz): transpose wrapped z-plane x fp32 (b,ic,s) -> xs[s][ic]
//   bf16 via 34-padded LDS staging (2 halves of 128 rows), then 9 taps of
//   MFMA: afrag = ds_read_b128 from wl, bfrag = ds_read_b128 from xs.
// LDS: 16KB xs + 17.4KB xsf + 27KB wl = 60.4KB (static, under 64KB).
__global__ __launch_bounds__(256, 1) void kConv(const float* __restrict__ x,
                                                const float* __restrict__ w_init,
                                                const float* __restrict__ w_qkv,
                                                float* __restrict__ out,
                                                ushort_t* __restrict__ Qbf,
                                                ushort_t* __restrict__ Kbf,
                                                ushort_t* __restrict__ VtTp) {
  __shared__ ushort_t wl[27 * 512];     // 27 KB
  __shared__ ushort_t xs[256 * 32];     // 16 KB: one z-plane, [s=y*16+x][ic]
  __shared__ float xsf[128 * 34];       // 17 KB: half-plane transpose staging
  int tid = threadIdx.x;
  int w = tid >> 6, lane = tid & 63;
  int quad = lane >> 4, nl = lane & 15;
  int bx = blockIdx.x;              // [0,256) = b*128 + z*8 + oq
  int oq = bx & 7;
  int z = (bx >> 3) & 15;
  int b = bx >> 7;

  // ---- Phase W: weight slice -> wl (contiguous 3456 float4 reads)
  const float* wsrc = (oq < 2) ? (w_init + (size_t)oq * 16 * 864)
                               : (w_qkv + (size_t)(oq - 2) * 16 * 864);  // 864=32*27
  const float QS = 0.35355339059327373f * 1.4426950408889634f;
  float wscale = (oq == 2 || oq == 3) ? QS : 1.0f;
#pragma unroll
  for (int i = 0; i < 14; ++i) {
    int idx4 = i * 256 + tid;          // float4 index [0, 3456)
    if (idx4 < 3456) {
      float4 v = *(const float4*)(wsrc + (size_t)idx4 * 4);
      float vv[4] = {v.x, v.y, v.z, v.w};
#pragma unroll
      for (int k = 0; k < 4; ++k) {
        int e = idx4 * 4 + k;          // = (oo*32 + ic)*27 + tap
        int tap = e % 27;
        int rest = e / 27;
        int ic = rest & 31;
        int oo = rest >> 5;
        wl[tap * 512 + ((ic >> 3) * 16 + oo) * 8 + (ic & 7)] = f2bf(vv[k] * wscale);
      }
    }
  }

  float4v acc[4];
#pragma unroll
  for (int st = 0; st < 4; ++st) acc[st] = (float4v){0.f, 0.f, 0.f, 0.f};
  int y0 = w * 4;

  for (int kz = 0; kz < 3; ++kz) {
    int zr = (z + kz + 15) & 15;
    // ---- Phase X: stage plane zr -> xs[s][ic] bf16, in 2 halves of 128 rows
#pragma unroll
    for (int h = 0; h < 2; ++h) {
      __syncthreads();   // xsf free (prev pack / prev kz's mfma reads done)
      int rloc = tid & 127;
      int ich = tid >> 7;              // 0..1 -> ic 0..15 / 16..31
#pragma unroll
      for (int icq = 0; icq < 16; ++icq) {
        int ic = ich * 16 + icq;
        xsf[rloc * 34 + ic] = x[((size_t)(b * 32 + ic) * 16 + zr) * 256 + h * 128 + rloc];
      }
      __syncthreads();
#pragma unroll
      for (int r = 0; r < 2; ++r) {
        int slot = r * 256 + tid;      // [0,512) = 128 rows x 4 ic-groups
        int sl = slot >> 2;
        int icg = slot & 3;
        ushort_t tmp[8];
#pragma unroll
        for (int jj = 0; jj < 8; ++jj) tmp[jj] = f2bf(xsf[sl * 34 + icg * 8 + jj]);
        *(short8*)(xs + (h * 128 + sl) * 32 + icg * 8) = *(short8*)tmp;
      }
    }
    __syncthreads();

    // ---- 9 taps of this kz-plane
#pragma unroll
    for (int kyx = 0; kyx < 9; ++kyx) {
      int ky = kyx / 3, kx = kyx % 3;
      int tap = kz * 9 + kyx;
      short8 afrag = *(const short8*)(wl + tap * 512 + lane * 8);
      int xsh = (nl + kx + 15) & 15;
#pragma unroll
      for (int st = 0; st < 4; ++st) {
        int yy = (y0 + st + ky + 15) & 15;
        short8 bfrag = *(const short8*)(xs + (yy * 16 + xsh) * 32 + quad * 8);
        acc[st] = __builtin_amdgcn_mfma_f32_16x16x32_bf16(afrag, bfrag, acc[st], 0, 0, 0);
      }
    }
  }

  // Epilogue. C layout: col = nl (spatial x), row = quad*4 + r (o in tile).
#pragma unroll
  for (int st = 0; st < 4; ++st) {
    int y = y0 + st;
    int s = z * 256 + y * 16 + nl;
    int mperm = 2 * nl + (y & 1);   // k'-interleave matching kAttn's P order
#pragma unroll
    for (int r = 0; r < 4; ++r) {
      float val = acc[st][r];
      int oo = (oq & 1) * 16 + quad * 4 + r;   // index within 32-ch group
      if (oq < 2) {
        out[(size_t)(b * 64 + oo) * 4096 + s] = val;
      } else if (oq < 4) {
        int h = oo >> 3, c = oo & 7;
        Qbf[((size_t)(b * 4 + h) * 4096 + s) * 8 + c] = f2bf(val);
      } else if (oq < 6) {
        int h = oo >> 3, c = oo & 7;
        Kbf[((size_t)(b * 4 + h) * 4096 + s) * 8 + c] = f2bf(val);
      } else {
        int h = oo >> 3, c = oo & 7;
        VtTp[((size_t)(b * 4 + h) * 8 + c) * 4096 + (size_t)(s & ~31) + mperm] = f2bf(val);
      }
    }
  }
}

// MFMA attention, key-split KSP, 2 n-tiles (32 query rows) per wave.
// Grid = 256*KSP blocks x 4 waves. Each wave: 32 rows x (4096/KSP) keys.
// K loaded FULL-WAVE (lane -> row m0+(lane&31)); two Q A-variants (k-octet
// 0 / 1) extract keys 0..15 / 16..31 from one load. P LDS round-trip
// read-BEFORE-write pipelined. PV B-operand: V ch 0..7, ones at v=8
// (row-sum l for free), zeros above.
template <int KSP>
__global__ __launch_bounds__(256) void kAttn(const ushort_t* __restrict__ Qbf,
                                             const ushort_t* __restrict__ Kbf,
                                             const ushort_t* __restrict__ VtTp,
                                             float* __restrict__ pacc,
                                             float* __restrict__ pl) {
  const int NCH = 128 / KSP;                  // 32-key chunks per wave
  __shared__ ushort_t Plds[4 * 2 * 2 * 640];  // [wave][tile][buf][16*40]
  int tid = threadIdx.x;
  int w = tid >> 6, lane = tid & 63;
  int id = blockIdx.x * 4 + w;               // [0, 1024*KSP)
  int bh = id / (KSP * 128);                 // [0,8)
  int rem = id % (KSP * 128);
  int ksp = rem >> 7;                        // key split [0,KSP)
  int ntile = rem & 127;                     // [0,128)
  int n0 = ntile * 32;
  int quad = lane >> 4, nl = lane & 15;
  int l31 = lane & 31;
  int v = nl;

  short8 z8 = {};
  short8 q0f = *(const short8*)(Qbf + ((size_t)bh * 4096 + n0 + nl) * 8);
  short8 q1f = *(const short8*)(Qbf + ((size_t)bh * 4096 + n0 + 16 + nl) * 8);
  short8 aq0A = (quad == 0) ? q0f : z8;   // tile0, Q in k-octet 0 -> keys 0..15
  short8 aq0B = (quad == 1) ? q0f : z8;   // tile0, Q in k-octet 1 -> keys 16..31
  short8 aq1A = (quad == 0) ? q1f : z8;
  short8 aq1B = (quad == 1) ? q1f : z8;

  short8 ones8;
#pragma unroll
  for (int i = 0; i < 8; ++i) ones8[i] = (short)0x3F80;  // bf16 1.0

  const ushort_t* Krows = Kbf + ((size_t)bh * 4096 + ksp * (4096 / KSP)) * 8;
  const ushort_t* Vrow = VtTp + ((size_t)bh * 8 + (v < 8 ? v : 0)) * 4096
                         + ksp * (4096 / KSP) + quad * 8;
  ushort_t* P0 = Plds + (w * 2 + 0) * 2 * 640;
  ushort_t* P1 = Plds + (w * 2 + 1) * 2 * 640;

  float4v acc0 = {}, acc1 = {};

#define QKEXP(mi, bkr)                                                         \
  {                                                                            \
    float4v s00 = __builtin_amdgcn_mfma_f32_16x16x32_bf16(                     \
        aq0A, bkr, (float4v){0.f, 0.f, 0.f, 0.f}, 0, 0, 0);                    \
    float4v s01 = __builtin_amdgcn_mfma_f32_16x16x32_bf16(                     \
        aq0B, bkr, (float4v){0.f, 0.f, 0.f, 0.f}, 0, 0, 0);                    \
    float4v s10 = __builtin_amdgcn_mfma_f32_16x16x32_bf16(                     \
        aq1A, bkr, (float4v){0.f, 0.f, 0.f, 0.f}, 0, 0, 0);                    \
    float4v s11 = __builtin_amdgcn_mfma_f32_16x16x32_bf16(                     \
        aq1B, bkr, (float4v){0.f, 0.f, 0.f, 0.f}, 0, 0, 0);                    \
    uint_t* Pt0 = (uint_t*)(P0 + ((mi) & 1) * 640);                            \
    uint_t* Pt1 = (uint_t*)(P1 + ((mi) & 1) * 640);                            \
    _Pragma("unroll") for (int r = 0; r < 4; ++r) {                            \
      Pt0[(quad * 4 + r) * 20 + nl] =                                          \
          cvtpk(__builtin_amdgcn_exp2f(s00[r]), __builtin_amdgcn_exp2f(s01[r]));\
      Pt1[(quad * 4 + r) * 20 + nl] =                                          \
          cvtpk(__builtin_amdgcn_exp2f(s10[r]), __builtin_amdgcn_exp2f(s11[r]));\
    }                                                                          \
  }

#define PVSTEP(a2, bv, accv)                                                   \
  {                                                                            \
    short8 b2 = (v < 8) ? (bv) : ((v == 8) ? ones8 : z8);                      \
    accv = __builtin_amdgcn_mfma_f32_16x16x32_bf16(a2, b2, accv, 0, 0, 0);     \
  }

  short8 bk = *(const short8*)(Krows + (size_t)l31 * 8);       // chunk 0
  QKEXP(0, bk)
  bk = *(const short8*)(Krows + (size_t)(32 + l31) * 8);       // chunk 1

#pragma unroll 2
  for (int mi = 1; mi < NCH; ++mi) {
    int pb = ((mi - 1) & 1) * 640;
    // read P(mi-1) FIRST: its latency hides under this chunk's QK/exp/writes
    short8 a20 = *(const short8*)(P0 + pb + nl * 40 + quad * 8);
    short8 a21 = *(const short8*)(P1 + pb + nl * 40 + quad * 8);
    short8 bv = *(const short8*)(Vrow + (mi - 1) * 32);
    QKEXP(mi, bk)
    int nxt = ((mi + 1) & (NCH - 1)) * 32;                     // wrap (dummy last)
    bk = *(const short8*)(Krows + (size_t)(nxt + l31) * 8);
    PVSTEP(a20, bv, acc0)
    PVSTEP(a21, bv, acc1)
  }
  {
    int pb = ((NCH - 1) & 1) * 640;
    short8 a20 = *(const short8*)(P0 + pb + nl * 40 + quad * 8);
    short8 a21 = *(const short8*)(P1 + pb + nl * 40 + quad * 8);
    short8 bv = *(const short8*)(Vrow + (NCH - 1) * 32);
    PVSTEP(a20, bv, acc0)
    PVSTEP(a21, bv, acc1)
  }
#undef QKEXP
#undef PVSTEP

  // acc: O-partial[n][v] at col=v=nl, row=quad*4+r; col 8 = partial row-sum l.
#pragma unroll
  for (int r = 0; r < 4; ++r) {
    int rq = quad * 4 + r;
    int rowg0 = bh * 4096 + n0 + rq;           // [0, 32768)
    int rowg1 = rowg0 + 16;
    if (v < 8) {
      pacc[((size_t)rowg0 * KSP + ksp) * 8 + v] = acc0[r];
      pacc[((size_t)rowg1 * KSP + ksp) * 8 + v] = acc1[r];
    } else if (v == 8) {
      pl[(size_t)rowg0 * KSP + ksp] = acc0[r];
      pl[(size_t)rowg1 * KSP + ksp] = acc1[r];
    }
  }
}

// Fused merge + 1x1x1 conv + bias -> out channels 32..63.
// Block = (b, 64-spatial tile); grid 128. Phase 1: merge the KSP key-split
// partials into LDS M[ci(32)][spl(64)] applying the reference's faithful
// reshape (attnR[ci][sp]: h=ci>>3, n=(ci&7)*512+(sp>>3), c=sp&7).
// Phase 2: 32->32 channel conv from LDS, coalesced stores.
template <int KSP>
__global__ __launch_bounds__(256) void kOut(const float* __restrict__ pacc,
                                            const float* __restrict__ pl,
                                            const float* __restrict__ w_out,
                                            const float* __restrict__ b_out,
                                            float* __restrict__ out) {
  __shared__ float M[32 * 64];   // 8 KB
  int bx = blockIdx.x;           // [0,128) = b*64 + spt
  int b = bx >> 6;
  int sp0 = (bx & 63) * 64;
  int t = threadIdx.x;

  // phase 1: thread t -> ci = t>>3, nsub = t&7
  {
    int ci = t >> 3, nsub = t & 7;
    int h = ci >> 3, tt = ci & 7;
    int n = tt * 512 + (sp0 >> 3) + nsub;
    size_t row = (size_t)(b * 4 + h) * 4096 + n;
    float l = 0.f;
#pragma unroll
    for (int s = 0; s < KSP; ++s) l += pl[row * KSP + s];
    float rl = 1.0f / l;
    float m[8];
#pragma unroll
    for (int c = 0; c < 8; ++c) m[c] = 0.f;
#pragma unroll
    for (int s = 0; s < KSP; ++s) {
      const float4 p0 = *(const float4*)(pacc + (row * KSP + s) * 8);
      const float4 p1 = *(const float4*)(pacc + (row * KSP + s) * 8 + 4);
      m[0] += p0.x; m[1] += p0.y; m[2] += p0.z; m[3] += p0.w;
      m[4] += p1.x; m[5] += p1.y; m[6] += p1.z; m[7] += p1.w;
    }
    float4 o0 = {m[0] * rl, m[1] * rl, m[2] * rl, m[3] * rl};
    float4 o1 = {m[4] * rl, m[5] * rl, m[6] * rl, m[7] * rl};
    *(float4*)(M + ci * 64 + nsub * 8) = o0;
    *(float4*)(M + ci * 64 + nsub * 8 + 4) = o1;
  }
  __syncthreads();

  // phase 2: thread t -> spl = t&63, co-group t>>6 (8 channels each)
  {
    int spl = t & 63;
    int cog = t >> 6;              // wave-uniform
    float a[32];
#pragma unroll
    for (int ci = 0; ci < 32; ++ci) a[ci] = M[ci * 64 + spl];
#pragma unroll
    for (int oo = 0; oo < 8; ++oo) {
      int co = cog * 8 + oo;
      float r = b_out[co];
#pragma unroll
      for (int ci = 0; ci < 32; ++ci) r = fmaf(w_out[co * 32 + ci], a[ci], r);
      out[(size_t)(b * 64 + 32 + co) * 4096 + sp0 + spl] = r;
    }
  }
}

extern "C" void kernel_launch(void* const* d_in, const int* in_sizes, int n_in,
                              void* d_out, int out_size, void* d_ws, size_t ws_size,
                              hipStream_t stream) {
  const float* x      = (const float*)d_in[0];
  const float* w_init = (const float*)d_in[1];
  const float* w_qkv  = (const float*)d_in[2];
  const float* w_out  = (const float*)d_in[3];
  const float* b_out  = (const float*)d_in[4];
  float* out = (float*)d_out;

  // ws layout (bytes): Qbf/Kbf/VtTp 524288 each | pacc KSP*1048576 |
  //   pl KSP*131072. KSP=8 needs 11.0 MB (measured ws_size = 256 MiB, so
  //   KSP=8 runs; guard kept as insurance for smaller ws).
  const size_t fixed = 3 * 524288;
  int KSP = (ws_size >= fixed + (size_t)8 * (1048576 + 131072)) ? 8 : 4;

  ushort_t* Qbf = (ushort_t*)d_ws;
  ushort_t* Kbf = Qbf + 262144;
  ushort_t* VtTp = Kbf + 262144;
  float* pacc = (float*)(VtTp + 262144);
  float* pl = pacc + (size_t)KSP * 262144;

  kConv <<<256, 256, 0, stream>>>(x, w_init, w_qkv, out, Qbf, Kbf, VtTp);
  if (KSP == 8) {
    kAttn<8><<<2048, 256, 0, stream>>>(Qbf, Kbf, VtTp, pacc, pl);
    kOut<8> <<<128, 256, 0, stream>>>(pacc, pl, w_out, b_out, out);
  } else {
    kAttn<4><<<1024, 256, 0, stream>>>(Qbf, Kbf, VtTp, pacc, pl);
    kOut<4> <<<128, 256, 0, stream>>>(pacc, pl, w_out, b_out, out);
  }
}